// Round 6
// baseline (581.482 us; speedup 1.0000x reference)
//
#include <hip/hip_runtime.h>
#include <hip/hip_bf16.h>

#define B_ 4
#define T_ 1024
#define D_ 512
#define H_ 8
#define S_ 16
#define HD_ 64
#define IT 4     // i-rows per WG (attnpv)
#define JTB 64   // j sub-tile in attnpv
#define NSUB 16  // all 1024 j per WG (no atomics)
#define ITS 8    // i-rows per WG (stats)

// ---------------- params: centers, inv_var, eff_amps, inv_temp ----------------
__global__ void k_params(const float* __restrict__ base_centers,
                         const float* __restrict__ center_deltas,
                         const float* __restrict__ log_scales,
                         const float* __restrict__ log_amps,
                         const float* __restrict__ movement_param,
                         const float* __restrict__ temperature,
                         float* __restrict__ centers,
                         float* __restrict__ inv_var,
                         float* __restrict__ eff_amps,
                         float* __restrict__ inv_temp) {
  int tid = blockIdx.x * blockDim.x + threadIdx.x;
  float move = (1.f / (1.f + __expf(-movement_param[0]))) * 0.2f;
  for (int i = tid; i < H_ * S_ * HD_; i += blockDim.x * gridDim.x)
    centers[i] = base_centers[i] + center_deltas[i] * move;
  if (tid < H_ * S_) {
    float sc = __expf(log_scales[tid]);
    sc = fminf(fmaxf(sc, 1e-4f), 5.f);
    float am = __expf(log_amps[tid]);
    am = fminf(fmaxf(am, 1e-6f), 10.f);
    inv_var[tid] = 1.f / (sc * sc + 1e-8f);
    eff_amps[tid] = (am > 0.001f) ? am : 0.f;
  }
  if (tid == 0) {
    float t = fminf(fmaxf(temperature[0], 0.01f), 10.f);
    inv_temp[0] = 1.f / t;
  }
}

// ---------------- fp32 GEMM: C[M,N] = A[M,K] @ Bw[N,K]^T, 128x128 tile ----------------
__global__ __launch_bounds__(256) void gemm128(const float* __restrict__ A,
                                               const float* __restrict__ Bw,
                                               float* __restrict__ C,
                                               int M, int N, int K) {
  __shared__ float As[16][132];
  __shared__ float Bs[16][132];
  const int tid = threadIdx.x;
  const int m0 = blockIdx.y * 128;
  const int n0 = blockIdx.x * 128;
  const int tx = tid & 15;
  const int ty = tid >> 4;
  float acc[8][8] = {};
  for (int k0 = 0; k0 < K; k0 += 16) {
#pragma unroll
    for (int l = 0; l < 2; ++l) {
      int idx = (tid + l * 256) * 4;
      int m = idx >> 4, kk = idx & 15;
      float4 v = *(const float4*)(A + (size_t)(m0 + m) * K + k0 + kk);
      As[kk + 0][m] = v.x; As[kk + 1][m] = v.y; As[kk + 2][m] = v.z; As[kk + 3][m] = v.w;
      float4 w = *(const float4*)(Bw + (size_t)(n0 + m) * K + k0 + kk);
      Bs[kk + 0][m] = w.x; Bs[kk + 1][m] = w.y; Bs[kk + 2][m] = w.z; Bs[kk + 3][m] = w.w;
    }
    __syncthreads();
#pragma unroll
    for (int kk = 0; kk < 16; ++kk) {
      float4 a0 = *(const float4*)&As[kk][ty * 4];
      float4 a1 = *(const float4*)&As[kk][64 + ty * 4];
      float4 b0 = *(const float4*)&Bs[kk][tx * 4];
      float4 b1 = *(const float4*)&Bs[kk][64 + tx * 4];
      float av[8] = {a0.x, a0.y, a0.z, a0.w, a1.x, a1.y, a1.z, a1.w};
      float bv[8] = {b0.x, b0.y, b0.z, b0.w, b1.x, b1.y, b1.z, b1.w};
#pragma unroll
      for (int i = 0; i < 8; ++i)
#pragma unroll
        for (int j = 0; j < 8; ++j)
          acc[i][j] += av[i] * bv[j];
    }
    __syncthreads();
  }
#pragma unroll
  for (int i = 0; i < 8; ++i) {
    int row = m0 + ((i >> 2) * 64) + ty * 4 + (i & 3);
#pragma unroll
    for (int jc = 0; jc < 2; ++jc) {
      float4 v = make_float4(acc[i][jc * 4 + 0], acc[i][jc * 4 + 1],
                             acc[i][jc * 4 + 2], acc[i][jc * 4 + 3]);
      *(float4*)(C + (size_t)row * N + n0 + jc * 64 + tx * 4) = v;
    }
  }
}

// ---------------- gaussian kernel weights: q_w (× 1/temp), k_w ----------------
__global__ __launch_bounds__(256) void k_gauss(const float* __restrict__ qkv,
                                               const float* __restrict__ centers,
                                               const float* __restrict__ inv_var,
                                               const float* __restrict__ eff_amps,
                                               const float* __restrict__ inv_temp,
                                               float* __restrict__ qw,
                                               float* __restrict__ kw) {
  int gid = blockIdx.x * blockDim.x + threadIdx.x;
  if (gid >= B_ * T_ * H_ * S_) return;
  int s = gid & 15;
  int h = (gid >> 4) & 7;
  int bt = gid >> 7;  // b*T + t
  const float* qrow = qkv + (size_t)bt * 1536 + h * 64;
  const float* krow = qrow + 512;
  const float* c = centers + (h * 16 + s) * 64;
  float qd = 0.f, kd = 0.f;
#pragma unroll
  for (int d = 0; d < 64; d += 4) {
    float4 cv = *(const float4*)(c + d);
    float4 qv = *(const float4*)(qrow + d);
    float4 kv = *(const float4*)(krow + d);
    float t;
    t = qv.x - cv.x; qd += t * t;
    t = qv.y - cv.y; qd += t * t;
    t = qv.z - cv.z; qd += t * t;
    t = qv.w - cv.w; qd += t * t;
    t = kv.x - cv.x; kd += t * t;
    t = kv.y - cv.y; kd += t * t;
    t = kv.z - cv.z; kd += t * t;
    t = kv.w - cv.w; kd += t * t;
  }
  qd = fminf(qd, 100.f);
  kd = fminf(kd, 100.f);
  float iv = inv_var[h * 16 + s];
  float ea = eff_amps[h * 16 + s];
  qw[gid] = __expf(-0.5f * qd * iv) * ea * inv_temp[0];
  kw[gid] = __expf(-0.5f * kd * iv) * ea;
}

__device__ __forceinline__ float dot16(const float4 q[4], const float4 k[4]) {
  return q[0].x * k[0].x + q[0].y * k[0].y + q[0].z * k[0].z + q[0].w * k[0].w +
         q[1].x * k[1].x + q[1].y * k[1].y + q[1].z * k[1].z + q[1].w * k[1].w +
         q[2].x * k[2].x + q[2].y * k[2].y + q[2].z * k[2].z + q[2].w * k[2].w +
         q[3].x * k[3].x + q[3].y * k[3].y + q[3].z * k[3].z + q[3].w * k[3].w;
}

// ---------------- softmax stats: m_i, 1/s_i per (b,h,i) ----------------
__global__ __launch_bounds__(256) void k_stats(const float* __restrict__ qw_g,
                                               const float* __restrict__ kw_g,
                                               float* __restrict__ m_g,
                                               float* __restrict__ is_g) {
  const int x = blockIdx.x;
  const int ic = x & 127;
  const int h = (x >> 7) & 7;
  const int b = x >> 10;
  const int i0 = ic * ITS;
  const int tid = threadIdx.x;

  __shared__ float qw_l[ITS * 16];
  __shared__ float red[4][ITS][2];

  if (tid < 32) {
    int r = tid >> 2, s4 = (tid & 3) * 4;
    *(float4*)&qw_l[r * 16 + s4] =
        *(const float4*)(qw_g + (((size_t)(b * T_ + i0 + r) * H_ + h) * S_ + s4));
  }
  __syncthreads();

  float m[ITS], s[ITS];
#pragma unroll
  for (int r = 0; r < ITS; ++r) { m[r] = -1e30f; s[r] = 0.f; }

  for (int c = 0; c < T_ / 256; ++c) {
    int j = c * 256 + tid;
    const float* kp = kw_g + ((size_t)(b * T_ + j) * H_ + h) * S_;
    float4 k4[4];
    k4[0] = *(const float4*)(kp);
    k4[1] = *(const float4*)(kp + 4);
    k4[2] = *(const float4*)(kp + 8);
    k4[3] = *(const float4*)(kp + 12);
#pragma unroll
    for (int r = 0; r < ITS; ++r) {
      float4 q4[4];
      q4[0] = *(const float4*)&qw_l[r * 16 + 0];
      q4[1] = *(const float4*)&qw_l[r * 16 + 4];
      q4[2] = *(const float4*)&qw_l[r * 16 + 8];
      q4[3] = *(const float4*)&qw_l[r * 16 + 12];
      float l = dot16(q4, k4);
      float mn = fmaxf(m[r], l);
      s[r] = s[r] * __expf(m[r] - mn) + __expf(l - mn);
      m[r] = mn;
    }
  }
#pragma unroll
  for (int o = 1; o < 64; o <<= 1) {
#pragma unroll
    for (int r = 0; r < ITS; ++r) {
      float m2 = __shfl_xor(m[r], o);
      float s2 = __shfl_xor(s[r], o);
      float mn = fmaxf(m[r], m2);
      s[r] = s[r] * __expf(m[r] - mn) + s2 * __expf(m2 - mn);
      m[r] = mn;
    }
  }
  int wv = tid >> 6;
  if ((tid & 63) == 0) {
#pragma unroll
    for (int r = 0; r < ITS; ++r) { red[wv][r][0] = m[r]; red[wv][r][1] = s[r]; }
  }
  __syncthreads();
  if (tid < ITS) {
    float mf = red[0][tid][0], sf = red[0][tid][1];
#pragma unroll
    for (int w = 1; w < 4; ++w) {
      float m2 = red[w][tid][0], s2 = red[w][tid][1];
      float mn = fmaxf(mf, m2);
      sf = sf * __expf(mf - mn) + s2 * __expf(m2 - mn);
      mf = mn;
    }
    size_t o = (size_t)(b * H_ + h) * T_ + i0 + tid;
    m_g[o] = mf;
    is_g[o] = 1.f / sf;
  }
}

// ---------------- attn values + PV (all j per WG; XCD-partitioned by b) ----------------
// grid: 1024 WGs of 256. bid&7 -> XCD (round-robin heuristic); b = (bid&7)>>1 so
// each XCD pair serves ONE batch: per-XCD L2 working set = V[b] 2MB + kw[b] 0.5MB
// < 4MB. PLAIN coalesced full-line stores (nontemporal stores in round 5 caused
// 4.8x write amplification + L2 thrash: WRITE 639MB, FETCH 264MB).
__global__ __launch_bounds__(256, 4) void k_attnpv(const float* __restrict__ qkv,
                                                   const float* __restrict__ qw_g,
                                                   const float* __restrict__ kw_g,
                                                   const float* __restrict__ m_g,
                                                   const float* __restrict__ is_g,
                                                   float* __restrict__ attn,
                                                   float* __restrict__ out_pre) {
  const int bid = blockIdx.x;
  const int x = bid & 7;
  const int b = x >> 1;
  const int it = ((bid >> 3) << 1) | (x & 1);  // 0..255
  const int i0 = it * IT;
  const int tid = threadIdx.x;

  __shared__ float qw_l[IT][H_ * S_];   // 2 KB
  __shared__ float msl[IT][H_];
  __shared__ float isl[IT][H_];
  __shared__ float tile[IT][H_][JTB + 4];  // 8.7 KB

  if (tid < 128) {
    int f = tid * 4;
    int r = f >> 7, c = f & 127;
    *(float4*)&qw_l[r][c] = *(const float4*)(qw_g + ((size_t)(b * T_ + i0 + r) * 128 + c));
  }
  if (tid < 32) {
    int r = tid >> 3, hh = tid & 7;
    size_t o = (size_t)(b * H_ + hh) * T_ + i0 + r;
    msl[r][hh] = m_g[o];
    isl[r][hh] = is_g[o];
  }
  __syncthreads();

  const int h = tid >> 5;
  const int jq = tid & 31;
  const int d0 = jq * 2;
  const float* kw_b = kw_g + (size_t)b * T_ * (H_ * S_);
  const float* v_b = qkv + (size_t)b * T_ * 1536 + 1024 + h * 64 + d0;
  float acc[IT][2];
#pragma unroll
  for (int r = 0; r < IT; ++r) { acc[r][0] = 0.f; acc[r][1] = 0.f; }
  float* attn_b = attn + (size_t)(b * T_ + i0) * (T_ * H_);

  for (int st = 0; st < NSUB; ++st) {
    const int j0 = st * JTB;
    // kw for this thread's 2 j's (32 VGPRs)
    const float* kp = kw_b + ((size_t)(j0 + jq * 2) * H_ + h) * S_;
    float4 ka[4], kb[4];
    ka[0] = *(const float4*)(kp);       ka[1] = *(const float4*)(kp + 4);
    ka[2] = *(const float4*)(kp + 8);   ka[3] = *(const float4*)(kp + 12);
    kb[0] = *(const float4*)(kp + 128); kb[1] = *(const float4*)(kp + 132);
    kb[2] = *(const float4*)(kp + 136); kb[3] = *(const float4*)(kp + 140);
#pragma unroll
    for (int r = 0; r < IT; ++r) {
      float4 q4[4];
      q4[0] = *(const float4*)&qw_l[r][h * 16 + 0];
      q4[1] = *(const float4*)&qw_l[r][h * 16 + 4];
      q4[2] = *(const float4*)&qw_l[r][h * 16 + 8];
      q4[3] = *(const float4*)&qw_l[r][h * 16 + 12];
      float la = dot16(q4, ka);
      float lb = dot16(q4, kb);
      float mm = msl[r][h], ii = isl[r][h];
      *(float2*)&tile[r][h][jq * 2] =
          make_float2(__expf(la - mm) * ii, __expf(lb - mm) * ii);
    }
    __syncthreads();
    // coalesced attn write: per r, 64 j x 8 h = 512 contiguous floats
#pragma unroll
    for (int l = 0; l < 2; ++l) {
      int f = (l * 256 + tid) * 4;
      int r = f >> 9;
      int rem = f & 511;
      int jl = rem >> 3;
      int h0 = rem & 7;  // 0 or 4
      float4 v;
      v.x = tile[r][h0 + 0][jl];
      v.y = tile[r][h0 + 1][jl];
      v.z = tile[r][h0 + 2][jl];
      v.w = tile[r][h0 + 3][jl];
      *(float4*)(attn_b + (size_t)r * (T_ * H_) + (size_t)(j0 + jl) * H_ + h0) = v;
    }
    // PV partial from LDS tile (broadcast reads within each h-group)
#pragma unroll
    for (int u4 = 0; u4 < JTB / 4; ++u4) {
      const float* vp = v_b + (size_t)(j0 + u4 * 4) * 1536;
      float2 v0 = *(const float2*)(vp);
      float2 v1 = *(const float2*)(vp + 1536);
      float2 v2 = *(const float2*)(vp + 3072);
      float2 v3 = *(const float2*)(vp + 4608);
#pragma unroll
      for (int r = 0; r < IT; ++r) {
        float4 a4 = *(const float4*)&tile[r][h][u4 * 4];
        acc[r][0] += a4.x * v0.x + a4.y * v1.x + a4.z * v2.x + a4.w * v3.x;
        acc[r][1] += a4.x * v0.y + a4.y * v1.y + a4.z * v2.y + a4.w * v3.y;
      }
    }
    __syncthreads();
  }
#pragma unroll
  for (int r = 0; r < IT; ++r) {
    *(float2*)(out_pre + (size_t)(b * T_ + i0 + r) * D_ + h * HD_ + d0) =
        make_float2(acc[r][0], acc[r][1]);
  }
}

extern "C" void kernel_launch(void* const* d_in, const int* in_sizes, int n_in,
                              void* d_out, int out_size, void* d_ws, size_t ws_size,
                              hipStream_t stream) {
  const float* x = (const float*)d_in[0];
  const float* qkv_w = (const float*)d_in[1];
  const float* out_w = (const float*)d_in[2];
  const float* base_c = (const float*)d_in[3];
  const float* deltas = (const float*)d_in[4];
  const float* log_sc = (const float*)d_in[5];
  const float* log_am = (const float*)d_in[6];
  const float* move_p = (const float*)d_in[7];
  const float* temp = (const float*)d_in[8];

  float* out = (float*)d_out;                    // B*T*D
  float* attn = out + (size_t)B_ * T_ * D_;      // B*T*T*H

  float* ws = (float*)d_ws;
  float* qkv = ws;                                          // 6,291,456
  float* qw = qkv + (size_t)B_ * T_ * 3 * D_;               // 524,288
  float* kw = qw + (size_t)B_ * T_ * H_ * S_;               // 524,288
  float* out_pre = kw + (size_t)B_ * T_ * H_ * S_;          // 2,097,152
  float* centers = out_pre + (size_t)B_ * T_ * D_;          // 8,192
  float* inv_var = centers + H_ * S_ * HD_;                 // 128
  float* eff_amps = inv_var + H_ * S_;                      // 128
  float* inv_temp = eff_amps + H_ * S_;                     // 4 (padded)
  float* m_g = inv_temp + 4;                                // 32,768
  float* is_g = m_g + (size_t)B_ * H_ * T_;                 // 32,768

  k_params<<<32, 256, 0, stream>>>(base_c, deltas, log_sc, log_am, move_p, temp,
                                   centers, inv_var, eff_amps, inv_temp);
  dim3 g1(1536 / 128, 4096 / 128);
  gemm128<<<g1, 256, 0, stream>>>(x, qkv_w, qkv, B_ * T_, 3 * D_, D_);
  k_gauss<<<(B_ * T_ * H_ * S_) / 256, 256, 0, stream>>>(qkv, centers, inv_var,
                                                         eff_amps, inv_temp, qw, kw);
  k_stats<<<B_ * H_ * (T_ / ITS), 256, 0, stream>>>(qw, kw, m_g, is_g);
  k_attnpv<<<B_ * (T_ / IT), 256, 0, stream>>>(qkv, qw, kw, m_g, is_g, attn, out_pre);
  dim3 g2(512 / 128, 4096 / 128);
  gemm128<<<g2, 256, 0, stream>>>(out_pre, out_w, out, B_ * T_, D_, D_);
}

// Round 7
// 426.027 us; speedup vs baseline: 1.3649x; 1.3649x over previous
//
#include <hip/hip_runtime.h>
#include <hip/hip_bf16.h>

#define B_ 4
#define T_ 1024
#define D_ 512
#define H_ 8
#define S_ 16
#define HD_ 64
#define ITS 8    // i-rows per WG (stats)
#define ITW 8    // i-rows per WG (attnw)
#define PVI 64   // i-rows per WG (pv)
#define PVJ 64   // j-chunk (pv)

// ---------------- params: centers, inv_var, eff_amps, inv_temp ----------------
__global__ void k_params(const float* __restrict__ base_centers,
                         const float* __restrict__ center_deltas,
                         const float* __restrict__ log_scales,
                         const float* __restrict__ log_amps,
                         const float* __restrict__ movement_param,
                         const float* __restrict__ temperature,
                         float* __restrict__ centers,
                         float* __restrict__ inv_var,
                         float* __restrict__ eff_amps,
                         float* __restrict__ inv_temp) {
  int tid = blockIdx.x * blockDim.x + threadIdx.x;
  float move = (1.f / (1.f + __expf(-movement_param[0]))) * 0.2f;
  for (int i = tid; i < H_ * S_ * HD_; i += blockDim.x * gridDim.x)
    centers[i] = base_centers[i] + center_deltas[i] * move;
  if (tid < H_ * S_) {
    float sc = __expf(log_scales[tid]);
    sc = fminf(fmaxf(sc, 1e-4f), 5.f);
    float am = __expf(log_amps[tid]);
    am = fminf(fmaxf(am, 1e-6f), 10.f);
    inv_var[tid] = 1.f / (sc * sc + 1e-8f);
    eff_amps[tid] = (am > 0.001f) ? am : 0.f;
  }
  if (tid == 0) {
    float t = fminf(fmaxf(temperature[0], 0.01f), 10.f);
    inv_temp[0] = 1.f / t;
  }
}

// ---------------- fp32 GEMM: C[M,N] = A[M,K] @ Bw[N,K]^T, 128x128 tile ----------------
__global__ __launch_bounds__(256) void gemm128(const float* __restrict__ A,
                                               const float* __restrict__ Bw,
                                               float* __restrict__ C,
                                               int M, int N, int K) {
  __shared__ float As[16][132];
  __shared__ float Bs[16][132];
  const int tid = threadIdx.x;
  const int m0 = blockIdx.y * 128;
  const int n0 = blockIdx.x * 128;
  const int tx = tid & 15;
  const int ty = tid >> 4;
  float acc[8][8] = {};
  for (int k0 = 0; k0 < K; k0 += 16) {
#pragma unroll
    for (int l = 0; l < 2; ++l) {
      int idx = (tid + l * 256) * 4;
      int m = idx >> 4, kk = idx & 15;
      float4 v = *(const float4*)(A + (size_t)(m0 + m) * K + k0 + kk);
      As[kk + 0][m] = v.x; As[kk + 1][m] = v.y; As[kk + 2][m] = v.z; As[kk + 3][m] = v.w;
      float4 w = *(const float4*)(Bw + (size_t)(n0 + m) * K + k0 + kk);
      Bs[kk + 0][m] = w.x; Bs[kk + 1][m] = w.y; Bs[kk + 2][m] = w.z; Bs[kk + 3][m] = w.w;
    }
    __syncthreads();
#pragma unroll
    for (int kk = 0; kk < 16; ++kk) {
      float4 a0 = *(const float4*)&As[kk][ty * 4];
      float4 a1 = *(const float4*)&As[kk][64 + ty * 4];
      float4 b0 = *(const float4*)&Bs[kk][tx * 4];
      float4 b1 = *(const float4*)&Bs[kk][64 + tx * 4];
      float av[8] = {a0.x, a0.y, a0.z, a0.w, a1.x, a1.y, a1.z, a1.w};
      float bv[8] = {b0.x, b0.y, b0.z, b0.w, b1.x, b1.y, b1.z, b1.w};
#pragma unroll
      for (int i = 0; i < 8; ++i)
#pragma unroll
        for (int j = 0; j < 8; ++j)
          acc[i][j] += av[i] * bv[j];
    }
    __syncthreads();
  }
#pragma unroll
  for (int i = 0; i < 8; ++i) {
    int row = m0 + ((i >> 2) * 64) + ty * 4 + (i & 3);
#pragma unroll
    for (int jc = 0; jc < 2; ++jc) {
      float4 v = make_float4(acc[i][jc * 4 + 0], acc[i][jc * 4 + 1],
                             acc[i][jc * 4 + 2], acc[i][jc * 4 + 3]);
      *(float4*)(C + (size_t)row * N + n0 + jc * 64 + tx * 4) = v;
    }
  }
}

// ---------------- gaussian kernel weights: q_w (× 1/temp), k_w ----------------
__global__ __launch_bounds__(256) void k_gauss(const float* __restrict__ qkv,
                                               const float* __restrict__ centers,
                                               const float* __restrict__ inv_var,
                                               const float* __restrict__ eff_amps,
                                               const float* __restrict__ inv_temp,
                                               float* __restrict__ qw,
                                               float* __restrict__ kw) {
  int gid = blockIdx.x * blockDim.x + threadIdx.x;
  if (gid >= B_ * T_ * H_ * S_) return;
  int s = gid & 15;
  int h = (gid >> 4) & 7;
  int bt = gid >> 7;  // b*T + t
  const float* qrow = qkv + (size_t)bt * 1536 + h * 64;
  const float* krow = qrow + 512;
  const float* c = centers + (h * 16 + s) * 64;
  float qd = 0.f, kd = 0.f;
#pragma unroll
  for (int d = 0; d < 64; d += 4) {
    float4 cv = *(const float4*)(c + d);
    float4 qv = *(const float4*)(qrow + d);
    float4 kv = *(const float4*)(krow + d);
    float t;
    t = qv.x - cv.x; qd += t * t;
    t = qv.y - cv.y; qd += t * t;
    t = qv.z - cv.z; qd += t * t;
    t = qv.w - cv.w; qd += t * t;
    t = kv.x - cv.x; kd += t * t;
    t = kv.y - cv.y; kd += t * t;
    t = kv.z - cv.z; kd += t * t;
    t = kv.w - cv.w; kd += t * t;
  }
  qd = fminf(qd, 100.f);
  kd = fminf(kd, 100.f);
  float iv = inv_var[h * 16 + s];
  float ea = eff_amps[h * 16 + s];
  qw[gid] = __expf(-0.5f * qd * iv) * ea * inv_temp[0];
  kw[gid] = __expf(-0.5f * kd * iv) * ea;
}

__device__ __forceinline__ float dot16(const float4 q[4], const float4 k[4]) {
  return q[0].x * k[0].x + q[0].y * k[0].y + q[0].z * k[0].z + q[0].w * k[0].w +
         q[1].x * k[1].x + q[1].y * k[1].y + q[1].z * k[1].z + q[1].w * k[1].w +
         q[2].x * k[2].x + q[2].y * k[2].y + q[2].z * k[2].z + q[2].w * k[2].w +
         q[3].x * k[3].x + q[3].y * k[3].y + q[3].z * k[3].z + q[3].w * k[3].w;
}

// ---------------- softmax stats: m_i, 1/s_i per (b,h,i) ----------------
__global__ __launch_bounds__(256) void k_stats(const float* __restrict__ qw_g,
                                               const float* __restrict__ kw_g,
                                               float* __restrict__ m_g,
                                               float* __restrict__ is_g) {
  const int x = blockIdx.x;
  const int ic = x & 127;
  const int h = (x >> 7) & 7;
  const int b = x >> 10;
  const int i0 = ic * ITS;
  const int tid = threadIdx.x;

  __shared__ float qw_l[ITS * 16];
  __shared__ float red[4][ITS][2];

  if (tid < 32) {
    int r = tid >> 2, s4 = (tid & 3) * 4;
    *(float4*)&qw_l[r * 16 + s4] =
        *(const float4*)(qw_g + (((size_t)(b * T_ + i0 + r) * H_ + h) * S_ + s4));
  }
  __syncthreads();

  float m[ITS], s[ITS];
#pragma unroll
  for (int r = 0; r < ITS; ++r) { m[r] = -1e30f; s[r] = 0.f; }

  for (int c = 0; c < T_ / 256; ++c) {
    int j = c * 256 + tid;
    const float* kp = kw_g + ((size_t)(b * T_ + j) * H_ + h) * S_;
    float4 k4[4];
    k4[0] = *(const float4*)(kp);
    k4[1] = *(const float4*)(kp + 4);
    k4[2] = *(const float4*)(kp + 8);
    k4[3] = *(const float4*)(kp + 12);
#pragma unroll
    for (int r = 0; r < ITS; ++r) {
      float4 q4[4];
      q4[0] = *(const float4*)&qw_l[r * 16 + 0];
      q4[1] = *(const float4*)&qw_l[r * 16 + 4];
      q4[2] = *(const float4*)&qw_l[r * 16 + 8];
      q4[3] = *(const float4*)&qw_l[r * 16 + 12];
      float l = dot16(q4, k4);
      float mn = fmaxf(m[r], l);
      s[r] = s[r] * __expf(m[r] - mn) + __expf(l - mn);
      m[r] = mn;
    }
  }
#pragma unroll
  for (int o = 1; o < 64; o <<= 1) {
#pragma unroll
    for (int r = 0; r < ITS; ++r) {
      float m2 = __shfl_xor(m[r], o);
      float s2 = __shfl_xor(s[r], o);
      float mn = fmaxf(m[r], m2);
      s[r] = s[r] * __expf(m[r] - mn) + s2 * __expf(m2 - mn);
      m[r] = mn;
    }
  }
  int wv = tid >> 6;
  if ((tid & 63) == 0) {
#pragma unroll
    for (int r = 0; r < ITS; ++r) { red[wv][r][0] = m[r]; red[wv][r][1] = s[r]; }
  }
  __syncthreads();
  if (tid < ITS) {
    float mf = red[0][tid][0], sf = red[0][tid][1];
#pragma unroll
    for (int w = 1; w < 4; ++w) {
      float m2 = red[w][tid][0], s2 = red[w][tid][1];
      float mn = fmaxf(mf, m2);
      sf = sf * __expf(mf - mn) + s2 * __expf(m2 - mn);
      mf = mn;
    }
    size_t o = (size_t)(b * H_ + h) * T_ + i0 + tid;
    m_g[o] = mf;
    is_g[o] = 1.f / sf;
  }
}

// ---------------- attn writer: recompute logits, write attn only ----------------
// grid: (jt fastest, it, b) = 2048 WGs of 256. Per WG: 8 i-rows x 256 j x 8 h.
// Round-2's pass-2 structure (measured clean: FETCH 15MB) minus PV/atomics.
__global__ __launch_bounds__(256, 4) void k_attnw(const float* __restrict__ qw_g,
                                                  const float* __restrict__ kw_g,
                                                  const float* __restrict__ m_g,
                                                  const float* __restrict__ is_g,
                                                  float* __restrict__ attn) {
  const int x = blockIdx.x;
  const int jt = x & 3;
  const int it = (x >> 2) & 127;
  const int b = x >> 9;
  const int i0 = it * ITW;
  const int jbase = jt * 256;
  const int tid = threadIdx.x;

  __shared__ float qw_l[ITW][H_ * S_];     // 4 KB
  __shared__ float msl[ITW][H_];
  __shared__ float isl[ITW][H_];
  __shared__ float tile[ITW][H_][68];      // 17.4 KB

  {
    int f = tid * 4;
    int r = f >> 7, c = f & 127;
    *(float4*)&qw_l[r][c] = *(const float4*)(qw_g + ((size_t)(b * T_ + i0 + r) * 128 + c));
  }
  if (tid < 64) {
    int r = tid >> 3, hh = tid & 7;
    size_t o = (size_t)(b * H_ + hh) * T_ + i0 + r;
    msl[r][hh] = m_g[o];
    isl[r][hh] = is_g[o];
  }
  __syncthreads();

  const int h = tid >> 5;
  const int jq = tid & 31;
  const float* kw_b = kw_g + (size_t)b * T_ * (H_ * S_);
  float* attn_b = attn + (size_t)(b * T_ + i0) * (T_ * H_);

  for (int st = 0; st < 4; ++st) {
    const int j0 = jbase + st * 64;
    const float* kp = kw_b + ((size_t)(j0 + jq * 2) * H_ + h) * S_;
    float4 ka[4], kb[4];
    ka[0] = *(const float4*)(kp);       ka[1] = *(const float4*)(kp + 4);
    ka[2] = *(const float4*)(kp + 8);   ka[3] = *(const float4*)(kp + 12);
    kb[0] = *(const float4*)(kp + 128); kb[1] = *(const float4*)(kp + 132);
    kb[2] = *(const float4*)(kp + 136); kb[3] = *(const float4*)(kp + 140);
#pragma unroll
    for (int r = 0; r < ITW; ++r) {
      float4 q4[4];
      q4[0] = *(const float4*)&qw_l[r][h * 16 + 0];
      q4[1] = *(const float4*)&qw_l[r][h * 16 + 4];
      q4[2] = *(const float4*)&qw_l[r][h * 16 + 8];
      q4[3] = *(const float4*)&qw_l[r][h * 16 + 12];
      float la = dot16(q4, ka);
      float lb = dot16(q4, kb);
      float mm = msl[r][h], ii = isl[r][h];
      *(float2*)&tile[r][h][jq * 2] =
          make_float2(__expf(la - mm) * ii, __expf(lb - mm) * ii);
    }
    __syncthreads();
    // coalesced attn write: per r, 64 j x 8 h = 512 contiguous floats
#pragma unroll
    for (int l = 0; l < 4; ++l) {
      int f = (l * 256 + tid) * 4;
      int r = f >> 9;
      int rem = f & 511;
      int jl = rem >> 3;
      int h0 = rem & 7;  // 0 or 4
      float4 v;
      v.x = tile[r][h0 + 0][jl];
      v.y = tile[r][h0 + 1][jl];
      v.z = tile[r][h0 + 2][jl];
      v.w = tile[r][h0 + 3][jl];
      *(float4*)(attn_b + (size_t)r * (T_ * H_) + (size_t)(j0 + jl) * H_ + h0) = v;
    }
    __syncthreads();
  }
}

// ---------------- PV as tiled GEMM with P-recompute ----------------
// grid 512 WGs of 256: XCD-swizzled so each XCD owns 4 (b,h) panels
// (V[b,h] 256KB + kw[b,h] 64KB; ~1.3MB per XCD, L2-resident).
// Per WG: 64 i-rows x 64 d (full head) over K=1024 j in chunks of 64.
// V panel read ONCE per 64 output rows -> total V demand 128MB (was 2GB).
__global__ __launch_bounds__(256) void k_pv(const float* __restrict__ qkv,
                                            const float* __restrict__ qw_g,
                                            const float* __restrict__ kw_g,
                                            const float* __restrict__ m_g,
                                            const float* __restrict__ is_g,
                                            float* __restrict__ out_pre) {
  const int bid = blockIdx.x;
  const int xcd = bid & 7;
  const int k = bid >> 3;              // 0..63
  const int p = xcd * 4 + (k & 3);     // panel 0..31
  const int ib = k >> 2;               // 0..15
  const int b = p >> 3;
  const int h = p & 7;
  const int i0 = ib * PVI;
  const int tid = threadIdx.x;

  __shared__ float qw_l[PVI][17];
  __shared__ float kw_l[PVJ][17];
  __shared__ float Vl[PVJ][68];
  __shared__ float Pl[PVJ][PVI + 4];
  __shared__ float msl[PVI];
  __shared__ float isl[PVI];

  // persistent qw panel: 64 i x 16
  {
    int i = tid >> 2, s4 = (tid & 3) * 4;
    float4 v = *(const float4*)(qw_g + (((size_t)(b * T_ + i0 + i) * H_ + h) * S_ + s4));
    qw_l[i][s4 + 0] = v.x; qw_l[i][s4 + 1] = v.y;
    qw_l[i][s4 + 2] = v.z; qw_l[i][s4 + 3] = v.w;
  }
  if (tid < PVI) {
    size_t o = (size_t)(b * H_ + h) * T_ + i0 + tid;
    msl[tid] = m_g[o];
    isl[tid] = is_g[o];
  }

  const int ty = tid >> 4;   // 0..15 -> i-quad
  const int tx = tid & 15;   // d-quad
  float acc[4][4] = {};

  for (int jc = 0; jc < T_ / PVJ; ++jc) {
    const int j0 = jc * PVJ;
    __syncthreads();  // protect kw_l/Vl/Pl from previous iteration readers
    // stage kw chunk: 64 j x 16
    {
      int j = tid >> 2, s4 = (tid & 3) * 4;
      float4 v = *(const float4*)(kw_g + (((size_t)(b * T_ + j0 + j) * H_ + h) * S_ + s4));
      kw_l[j][s4 + 0] = v.x; kw_l[j][s4 + 1] = v.y;
      kw_l[j][s4 + 2] = v.z; kw_l[j][s4 + 3] = v.w;
    }
    // stage V chunk: 64 j x 64 d
    {
      int j = tid >> 4, d4 = (tid & 15) * 4;
#pragma unroll
      for (int u = 0; u < 4; ++u) {
        float4 v = *(const float4*)(qkv + (size_t)(b * T_ + j0 + j + u * 16) * 1536 +
                                    1024 + h * 64 + d4);
        *(float4*)&Vl[j + u * 16][d4] = v;
      }
    }
    __syncthreads();
    // phase 1: P chunk (64 j x 64 i), 16 values/thread
#pragma unroll
    for (int u = 0; u < 16; ++u) {
      int flat = u * 256 + tid;
      int j = flat >> 6;
      int i = flat & 63;
      float d = 0.f;
#pragma unroll
      for (int s = 0; s < 16; ++s) d += qw_l[i][s] * kw_l[j][s];
      Pl[j][i] = __expf(d - msl[i]) * isl[i];
    }
    __syncthreads();
    // phase 2: acc += P^T x V over this chunk
#pragma unroll 8
    for (int j = 0; j < PVJ; ++j) {
      float4 pv = *(const float4*)&Pl[j][ty * 4];
      float4 vv = *(const float4*)&Vl[j][tx * 4];
      acc[0][0] += pv.x * vv.x; acc[0][1] += pv.x * vv.y;
      acc[0][2] += pv.x * vv.z; acc[0][3] += pv.x * vv.w;
      acc[1][0] += pv.y * vv.x; acc[1][1] += pv.y * vv.y;
      acc[1][2] += pv.y * vv.z; acc[1][3] += pv.y * vv.w;
      acc[2][0] += pv.z * vv.x; acc[2][1] += pv.z * vv.y;
      acc[2][2] += pv.z * vv.z; acc[2][3] += pv.z * vv.w;
      acc[3][0] += pv.w * vv.x; acc[3][1] += pv.w * vv.y;
      acc[3][2] += pv.w * vv.z; acc[3][3] += pv.w * vv.w;
    }
  }
#pragma unroll
  for (int ii = 0; ii < 4; ++ii) {
    *(float4*)(out_pre + (size_t)(b * T_ + i0 + ty * 4 + ii) * D_ + h * HD_ + tx * 4) =
        make_float4(acc[ii][0], acc[ii][1], acc[ii][2], acc[ii][3]);
  }
}

extern "C" void kernel_launch(void* const* d_in, const int* in_sizes, int n_in,
                              void* d_out, int out_size, void* d_ws, size_t ws_size,
                              hipStream_t stream) {
  const float* x = (const float*)d_in[0];
  const float* qkv_w = (const float*)d_in[1];
  const float* out_w = (const float*)d_in[2];
  const float* base_c = (const float*)d_in[3];
  const float* deltas = (const float*)d_in[4];
  const float* log_sc = (const float*)d_in[5];
  const float* log_am = (const float*)d_in[6];
  const float* move_p = (const float*)d_in[7];
  const float* temp = (const float*)d_in[8];

  float* out = (float*)d_out;                    // B*T*D
  float* attn = out + (size_t)B_ * T_ * D_;      // B*T*T*H

  float* ws = (float*)d_ws;
  float* qkv = ws;                                          // 6,291,456
  float* qw = qkv + (size_t)B_ * T_ * 3 * D_;               // 524,288
  float* kw = qw + (size_t)B_ * T_ * H_ * S_;               // 524,288
  float* out_pre = kw + (size_t)B_ * T_ * H_ * S_;          // 2,097,152
  float* centers = out_pre + (size_t)B_ * T_ * D_;          // 8,192
  float* inv_var = centers + H_ * S_ * HD_;                 // 128
  float* eff_amps = inv_var + H_ * S_;                      // 128
  float* inv_temp = eff_amps + H_ * S_;                     // 4 (padded)
  float* m_g = inv_temp + 4;                                // 32,768
  float* is_g = m_g + (size_t)B_ * H_ * T_;                 // 32,768

  k_params<<<32, 256, 0, stream>>>(base_c, deltas, log_sc, log_am, move_p, temp,
                                   centers, inv_var, eff_amps, inv_temp);
  dim3 g1(1536 / 128, 4096 / 128);
  gemm128<<<g1, 256, 0, stream>>>(x, qkv_w, qkv, B_ * T_, 3 * D_, D_);
  k_gauss<<<(B_ * T_ * H_ * S_) / 256, 256, 0, stream>>>(qkv, centers, inv_var,
                                                         eff_amps, inv_temp, qw, kw);
  k_stats<<<B_ * H_ * (T_ / ITS), 256, 0, stream>>>(qw, kw, m_g, is_g);
  k_attnw<<<B_ * (T_ / ITW) * 4, 256, 0, stream>>>(qw, kw, m_g, is_g, attn);
  k_pv<<<B_ * H_ * (T_ / PVI), 256, 0, stream>>>(qkv, qw, kw, m_g, is_g, out_pre);
  dim3 g2(512 / 128, 4096 / 128);
  gemm128<<<g2, 256, 0, stream>>>(out_pre, out_w, out, B_ * T_, D_, D_);
}

// Round 8
// 386.405 us; speedup vs baseline: 1.5049x; 1.1025x over previous
//
#include <hip/hip_runtime.h>
#include <hip/hip_bf16.h>

#define B_ 4
#define T_ 1024
#define D_ 512
#define H_ 8
#define S_ 16
#define HD_ 64
#define ITS 8    // i-rows per WG (stats)
#define ITW 8    // i-rows per WG (attnw)
#define PVI 32   // i-rows per WG (pv)  [64->32: grid 512->1024, 2->4 WG/CU]
#define PVJ 64   // j-chunk (pv)

// ---------------- params: centers, inv_var, eff_amps, inv_temp ----------------
__global__ void k_params(const float* __restrict__ base_centers,
                         const float* __restrict__ center_deltas,
                         const float* __restrict__ log_scales,
                         const float* __restrict__ log_amps,
                         const float* __restrict__ movement_param,
                         const float* __restrict__ temperature,
                         float* __restrict__ centers,
                         float* __restrict__ inv_var,
                         float* __restrict__ eff_amps,
                         float* __restrict__ inv_temp) {
  int tid = blockIdx.x * blockDim.x + threadIdx.x;
  float move = (1.f / (1.f + __expf(-movement_param[0]))) * 0.2f;
  for (int i = tid; i < H_ * S_ * HD_; i += blockDim.x * gridDim.x)
    centers[i] = base_centers[i] + center_deltas[i] * move;
  if (tid < H_ * S_) {
    float sc = __expf(log_scales[tid]);
    sc = fminf(fmaxf(sc, 1e-4f), 5.f);
    float am = __expf(log_amps[tid]);
    am = fminf(fmaxf(am, 1e-6f), 10.f);
    inv_var[tid] = 1.f / (sc * sc + 1e-8f);
    eff_amps[tid] = (am > 0.001f) ? am : 0.f;
  }
  if (tid == 0) {
    float t = fminf(fmaxf(temperature[0], 0.01f), 10.f);
    inv_temp[0] = 1.f / t;
  }
}

// ---------------- fp32 GEMM: C[M,N] = A[M,K] @ Bw[N,K]^T, BMxBN tile ----------------
// Tile sizes chosen per-call for grid occupancy: QKV 128x64 (768 WGs),
// out-proj 64x64 (512 WGs). Old fixed 128x128: 384 / 128 WGs (0.5-1.5 WG/CU).
template <int BM, int BN>
__global__ __launch_bounds__(256) void gemm_t(const float* __restrict__ A,
                                              const float* __restrict__ Bw,
                                              float* __restrict__ C,
                                              int M, int N, int K) {
  __shared__ float As[16][BM + 4];
  __shared__ float Bs[16][BN + 4];
  const int tid = threadIdx.x;
  const int m0 = blockIdx.y * BM;
  const int n0 = blockIdx.x * BN;
  const int tx = tid & 15;
  const int ty = tid >> 4;
  constexpr int TM = BM / 16;
  constexpr int TN = BN / 16;
  float acc[TM][TN] = {};
  for (int k0 = 0; k0 < K; k0 += 16) {
#pragma unroll
    for (int l = 0; l < BM / 64; ++l) {
      int idx = (tid + l * 256) * 4;
      int m = idx >> 4, kk = idx & 15;
      float4 v = *(const float4*)(A + (size_t)(m0 + m) * K + k0 + kk);
      As[kk + 0][m] = v.x; As[kk + 1][m] = v.y; As[kk + 2][m] = v.z; As[kk + 3][m] = v.w;
    }
#pragma unroll
    for (int l = 0; l < BN / 64; ++l) {
      int idx = (tid + l * 256) * 4;
      int m = idx >> 4, kk = idx & 15;
      float4 w = *(const float4*)(Bw + (size_t)(n0 + m) * K + k0 + kk);
      Bs[kk + 0][m] = w.x; Bs[kk + 1][m] = w.y; Bs[kk + 2][m] = w.z; Bs[kk + 3][m] = w.w;
    }
    __syncthreads();
#pragma unroll
    for (int kk = 0; kk < 16; ++kk) {
      float av[TM], bv[TN];
#pragma unroll
      for (int u = 0; u < TM / 4; ++u) {
        float4 a = *(const float4*)&As[kk][u * 64 + ty * 4];
        av[u * 4 + 0] = a.x; av[u * 4 + 1] = a.y;
        av[u * 4 + 2] = a.z; av[u * 4 + 3] = a.w;
      }
#pragma unroll
      for (int u = 0; u < TN / 4; ++u) {
        float4 b = *(const float4*)&Bs[kk][u * 64 + tx * 4];
        bv[u * 4 + 0] = b.x; bv[u * 4 + 1] = b.y;
        bv[u * 4 + 2] = b.z; bv[u * 4 + 3] = b.w;
      }
#pragma unroll
      for (int i = 0; i < TM; ++i)
#pragma unroll
        for (int j = 0; j < TN; ++j)
          acc[i][j] += av[i] * bv[j];
    }
    __syncthreads();
  }
#pragma unroll
  for (int i = 0; i < TM; ++i) {
    int row = m0 + (i >> 2) * 64 + ty * 4 + (i & 3);
#pragma unroll
    for (int jc = 0; jc < TN / 4; ++jc) {
      float4 v = make_float4(acc[i][jc * 4 + 0], acc[i][jc * 4 + 1],
                             acc[i][jc * 4 + 2], acc[i][jc * 4 + 3]);
      *(float4*)(C + (size_t)row * N + n0 + jc * 64 + tx * 4) = v;
    }
  }
}

// ---------------- gaussian kernel weights: q_w (× 1/temp), k_w ----------------
__global__ __launch_bounds__(256) void k_gauss(const float* __restrict__ qkv,
                                               const float* __restrict__ centers,
                                               const float* __restrict__ inv_var,
                                               const float* __restrict__ eff_amps,
                                               const float* __restrict__ inv_temp,
                                               float* __restrict__ qw,
                                               float* __restrict__ kw) {
  int gid = blockIdx.x * blockDim.x + threadIdx.x;
  if (gid >= B_ * T_ * H_ * S_) return;
  int s = gid & 15;
  int h = (gid >> 4) & 7;
  int bt = gid >> 7;  // b*T + t
  const float* qrow = qkv + (size_t)bt * 1536 + h * 64;
  const float* krow = qrow + 512;
  const float* c = centers + (h * 16 + s) * 64;
  float qd = 0.f, kd = 0.f;
#pragma unroll
  for (int d = 0; d < 64; d += 4) {
    float4 cv = *(const float4*)(c + d);
    float4 qv = *(const float4*)(qrow + d);
    float4 kv = *(const float4*)(krow + d);
    float t;
    t = qv.x - cv.x; qd += t * t;
    t = qv.y - cv.y; qd += t * t;
    t = qv.z - cv.z; qd += t * t;
    t = qv.w - cv.w; qd += t * t;
    t = kv.x - cv.x; kd += t * t;
    t = kv.y - cv.y; kd += t * t;
    t = kv.z - cv.z; kd += t * t;
    t = kv.w - cv.w; kd += t * t;
  }
  qd = fminf(qd, 100.f);
  kd = fminf(kd, 100.f);
  float iv = inv_var[h * 16 + s];
  float ea = eff_amps[h * 16 + s];
  qw[gid] = __expf(-0.5f * qd * iv) * ea * inv_temp[0];
  kw[gid] = __expf(-0.5f * kd * iv) * ea;
}

__device__ __forceinline__ float dot16(const float4 q[4], const float4 k[4]) {
  return q[0].x * k[0].x + q[0].y * k[0].y + q[0].z * k[0].z + q[0].w * k[0].w +
         q[1].x * k[1].x + q[1].y * k[1].y + q[1].z * k[1].z + q[1].w * k[1].w +
         q[2].x * k[2].x + q[2].y * k[2].y + q[2].z * k[2].z + q[2].w * k[2].w +
         q[3].x * k[3].x + q[3].y * k[3].y + q[3].z * k[3].z + q[3].w * k[3].w;
}

// ---------------- softmax stats: m_i, 1/s_i per (b,h,i) ----------------
__global__ __launch_bounds__(256) void k_stats(const float* __restrict__ qw_g,
                                               const float* __restrict__ kw_g,
                                               float* __restrict__ m_g,
                                               float* __restrict__ is_g) {
  const int x = blockIdx.x;
  const int ic = x & 127;
  const int h = (x >> 7) & 7;
  const int b = x >> 10;
  const int i0 = ic * ITS;
  const int tid = threadIdx.x;

  __shared__ float qw_l[ITS * 16];
  __shared__ float red[4][ITS][2];

  if (tid < 32) {
    int r = tid >> 2, s4 = (tid & 3) * 4;
    *(float4*)&qw_l[r * 16 + s4] =
        *(const float4*)(qw_g + (((size_t)(b * T_ + i0 + r) * H_ + h) * S_ + s4));
  }
  __syncthreads();

  float m[ITS], s[ITS];
#pragma unroll
  for (int r = 0; r < ITS; ++r) { m[r] = -1e30f; s[r] = 0.f; }

  for (int c = 0; c < T_ / 256; ++c) {
    int j = c * 256 + tid;
    const float* kp = kw_g + ((size_t)(b * T_ + j) * H_ + h) * S_;
    float4 k4[4];
    k4[0] = *(const float4*)(kp);
    k4[1] = *(const float4*)(kp + 4);
    k4[2] = *(const float4*)(kp + 8);
    k4[3] = *(const float4*)(kp + 12);
#pragma unroll
    for (int r = 0; r < ITS; ++r) {
      float4 q4[4];
      q4[0] = *(const float4*)&qw_l[r * 16 + 0];
      q4[1] = *(const float4*)&qw_l[r * 16 + 4];
      q4[2] = *(const float4*)&qw_l[r * 16 + 8];
      q4[3] = *(const float4*)&qw_l[r * 16 + 12];
      float l = dot16(q4, k4);
      float mn = fmaxf(m[r], l);
      s[r] = s[r] * __expf(m[r] - mn) + __expf(l - mn);
      m[r] = mn;
    }
  }
#pragma unroll
  for (int o = 1; o < 64; o <<= 1) {
#pragma unroll
    for (int r = 0; r < ITS; ++r) {
      float m2 = __shfl_xor(m[r], o);
      float s2 = __shfl_xor(s[r], o);
      float mn = fmaxf(m[r], m2);
      s[r] = s[r] * __expf(m[r] - mn) + s2 * __expf(m2 - mn);
      m[r] = mn;
    }
  }
  int wv = tid >> 6;
  if ((tid & 63) == 0) {
#pragma unroll
    for (int r = 0; r < ITS; ++r) { red[wv][r][0] = m[r]; red[wv][r][1] = s[r]; }
  }
  __syncthreads();
  if (tid < ITS) {
    float mf = red[0][tid][0], sf = red[0][tid][1];
#pragma unroll
    for (int w = 1; w < 4; ++w) {
      float m2 = red[w][tid][0], s2 = red[w][tid][1];
      float mn = fmaxf(mf, m2);
      sf = sf * __expf(mf - mn) + s2 * __expf(m2 - mn);
      mf = mn;
    }
    size_t o = (size_t)(b * H_ + h) * T_ + i0 + tid;
    m_g[o] = mf;
    is_g[o] = 1.f / sf;
  }
}

// ---------------- attn writer: recompute logits, write attn only ----------------
// grid: (jt fastest, it, b) = 2048 WGs of 256. Per WG: 8 i-rows x 256 j x 8 h.
__global__ __launch_bounds__(256, 4) void k_attnw(const float* __restrict__ qw_g,
                                                  const float* __restrict__ kw_g,
                                                  const float* __restrict__ m_g,
                                                  const float* __restrict__ is_g,
                                                  float* __restrict__ attn) {
  const int x = blockIdx.x;
  const int jt = x & 3;
  const int it = (x >> 2) & 127;
  const int b = x >> 9;
  const int i0 = it * ITW;
  const int jbase = jt * 256;
  const int tid = threadIdx.x;

  __shared__ float qw_l[ITW][H_ * S_];     // 4 KB
  __shared__ float msl[ITW][H_];
  __shared__ float isl[ITW][H_];
  __shared__ float tile[ITW][H_][68];      // 17.4 KB

  {
    int f = tid * 4;
    int r = f >> 7, c = f & 127;
    *(float4*)&qw_l[r][c] = *(const float4*)(qw_g + ((size_t)(b * T_ + i0 + r) * 128 + c));
  }
  if (tid < 64) {
    int r = tid >> 3, hh = tid & 7;
    size_t o = (size_t)(b * H_ + hh) * T_ + i0 + r;
    msl[r][hh] = m_g[o];
    isl[r][hh] = is_g[o];
  }
  __syncthreads();

  const int h = tid >> 5;
  const int jq = tid & 31;
  const float* kw_b = kw_g + (size_t)b * T_ * (H_ * S_);
  float* attn_b = attn + (size_t)(b * T_ + i0) * (T_ * H_);

  for (int st = 0; st < 4; ++st) {
    const int j0 = jbase + st * 64;
    const float* kp = kw_b + ((size_t)(j0 + jq * 2) * H_ + h) * S_;
    float4 ka[4], kb[4];
    ka[0] = *(const float4*)(kp);       ka[1] = *(const float4*)(kp + 4);
    ka[2] = *(const float4*)(kp + 8);   ka[3] = *(const float4*)(kp + 12);
    kb[0] = *(const float4*)(kp + 128); kb[1] = *(const float4*)(kp + 132);
    kb[2] = *(const float4*)(kp + 136); kb[3] = *(const float4*)(kp + 140);
#pragma unroll
    for (int r = 0; r < ITW; ++r) {
      float4 q4[4];
      q4[0] = *(const float4*)&qw_l[r][h * 16 + 0];
      q4[1] = *(const float4*)&qw_l[r][h * 16 + 4];
      q4[2] = *(const float4*)&qw_l[r][h * 16 + 8];
      q4[3] = *(const float4*)&qw_l[r][h * 16 + 12];
      float la = dot16(q4, ka);
      float lb = dot16(q4, kb);
      float mm = msl[r][h], ii = isl[r][h];
      *(float2*)&tile[r][h][jq * 2] =
          make_float2(__expf(la - mm) * ii, __expf(lb - mm) * ii);
    }
    __syncthreads();
#pragma unroll
    for (int l = 0; l < 4; ++l) {
      int f = (l * 256 + tid) * 4;
      int r = f >> 9;
      int rem = f & 511;
      int jl = rem >> 3;
      int h0 = rem & 7;  // 0 or 4
      float4 v;
      v.x = tile[r][h0 + 0][jl];
      v.y = tile[r][h0 + 1][jl];
      v.z = tile[r][h0 + 2][jl];
      v.w = tile[r][h0 + 3][jl];
      *(float4*)(attn_b + (size_t)r * (T_ * H_) + (size_t)(j0 + jl) * H_ + h0) = v;
    }
    __syncthreads();
  }
}

// ---------------- PV as tiled GEMM with P-recompute ----------------
// grid 1024 WGs of 256 (was 512): XCD-swizzled, each XCD owns 4 (b,h) panels
// (~1.3MB, L2-resident). Per WG: 32 i-rows x 64 d over K=1024 j in chunks of 64.
// LDS 33KB -> 4 WG/CU; grid gives 4 WG/CU = 16 waves/CU (round 7: 8).
__global__ __launch_bounds__(256) void k_pv(const float* __restrict__ qkv,
                                            const float* __restrict__ qw_g,
                                            const float* __restrict__ kw_g,
                                            const float* __restrict__ m_g,
                                            const float* __restrict__ is_g,
                                            float* __restrict__ out_pre) {
  const int bid = blockIdx.x;
  const int xcd = bid & 7;
  const int q = bid >> 3;              // 0..127
  const int p = xcd * 4 + (q & 3);     // panel 0..31
  const int ib = q >> 2;               // 0..31
  const int b = p >> 3;
  const int h = p & 7;
  const int i0 = ib * PVI;
  const int tid = threadIdx.x;

  __shared__ float qw_l[PVI][17];
  __shared__ float kw_l[PVJ][17];
  __shared__ float Vl[PVJ][68];
  __shared__ float Pl[PVJ][PVI + 4];
  __shared__ float msl[PVI];
  __shared__ float isl[PVI];

  // persistent qw panel: 32 i x 16
  if (tid < 128) {
    int i = tid >> 2, s4 = (tid & 3) * 4;
    float4 v = *(const float4*)(qw_g + (((size_t)(b * T_ + i0 + i) * H_ + h) * S_ + s4));
    qw_l[i][s4 + 0] = v.x; qw_l[i][s4 + 1] = v.y;
    qw_l[i][s4 + 2] = v.z; qw_l[i][s4 + 3] = v.w;
  }
  if (tid < PVI) {
    size_t o = (size_t)(b * H_ + h) * T_ + i0 + tid;
    msl[tid] = m_g[o];
    isl[tid] = is_g[o];
  }

  const int ty = tid >> 4;   // 0..15 -> i-pair
  const int tx = tid & 15;   // d-quad
  float acc[2][4] = {};

  for (int jc = 0; jc < T_ / PVJ; ++jc) {
    const int j0 = jc * PVJ;
    __syncthreads();  // protect kw_l/Vl/Pl from previous iteration readers
    // stage kw chunk: 64 j x 16
    {
      int j = tid >> 2, s4 = (tid & 3) * 4;
      float4 v = *(const float4*)(kw_g + (((size_t)(b * T_ + j0 + j) * H_ + h) * S_ + s4));
      kw_l[j][s4 + 0] = v.x; kw_l[j][s4 + 1] = v.y;
      kw_l[j][s4 + 2] = v.z; kw_l[j][s4 + 3] = v.w;
    }
    // stage V chunk: 64 j x 64 d
    {
      int j = tid >> 4, d4 = (tid & 15) * 4;
#pragma unroll
      for (int u = 0; u < 4; ++u) {
        float4 v = *(const float4*)(qkv + (size_t)(b * T_ + j0 + j + u * 16) * 1536 +
                                    1024 + h * 64 + d4);
        *(float4*)&Vl[j + u * 16][d4] = v;
      }
    }
    __syncthreads();
    // phase 1: P chunk (64 j x 32 i), 8 values/thread
#pragma unroll
    for (int u = 0; u < 8; ++u) {
      int flat = u * 256 + tid;
      int j = flat >> 5;
      int i = flat & 31;
      float d = 0.f;
#pragma unroll
      for (int s = 0; s < 16; ++s) d += qw_l[i][s] * kw_l[j][s];
      Pl[j][i] = __expf(d - msl[i]) * isl[i];
    }
    __syncthreads();
    // phase 2: acc += P^T x V over this chunk
#pragma unroll 8
    for (int j = 0; j < PVJ; ++j) {
      float2 pv = *(const float2*)&Pl[j][ty * 2];
      float4 vv = *(const float4*)&Vl[j][tx * 4];
      acc[0][0] += pv.x * vv.x; acc[0][1] += pv.x * vv.y;
      acc[0][2] += pv.x * vv.z; acc[0][3] += pv.x * vv.w;
      acc[1][0] += pv.y * vv.x; acc[1][1] += pv.y * vv.y;
      acc[1][2] += pv.y * vv.z; acc[1][3] += pv.y * vv.w;
    }
  }
#pragma unroll
  for (int ii = 0; ii < 2; ++ii) {
    *(float4*)(out_pre + (size_t)(b * T_ + i0 + ty * 2 + ii) * D_ + h * HD_ + tx * 4) =
        make_float4(acc[ii][0], acc[ii][1], acc[ii][2], acc[ii][3]);
  }
}

extern "C" void kernel_launch(void* const* d_in, const int* in_sizes, int n_in,
                              void* d_out, int out_size, void* d_ws, size_t ws_size,
                              hipStream_t stream) {
  const float* x = (const float*)d_in[0];
  const float* qkv_w = (const float*)d_in[1];
  const float* out_w = (const float*)d_in[2];
  const float* base_c = (const float*)d_in[3];
  const float* deltas = (const float*)d_in[4];
  const float* log_sc = (const float*)d_in[5];
  const float* log_am = (const float*)d_in[6];
  const float* move_p = (const float*)d_in[7];
  const float* temp = (const float*)d_in[8];

  float* out = (float*)d_out;                    // B*T*D
  float* attn = out + (size_t)B_ * T_ * D_;      // B*T*T*H

  float* ws = (float*)d_ws;
  float* qkv = ws;                                          // 6,291,456
  float* qw = qkv + (size_t)B_ * T_ * 3 * D_;               // 524,288
  float* kw = qw + (size_t)B_ * T_ * H_ * S_;               // 524,288
  float* out_pre = kw + (size_t)B_ * T_ * H_ * S_;          // 2,097,152
  float* centers = out_pre + (size_t)B_ * T_ * D_;          // 8,192
  float* inv_var = centers + H_ * S_ * HD_;                 // 128
  float* eff_amps = inv_var + H_ * S_;                      // 128
  float* inv_temp = eff_amps + H_ * S_;                     // 4 (padded)
  float* m_g = inv_temp + 4;                                // 32,768
  float* is_g = m_g + (size_t)B_ * H_ * T_;                 // 32,768

  k_params<<<32, 256, 0, stream>>>(base_c, deltas, log_sc, log_am, move_p, temp,
                                   centers, inv_var, eff_amps, inv_temp);
  dim3 g1(1536 / 64, 4096 / 128);   // 24 x 32 = 768 WGs
  gemm_t<128, 64><<<g1, 256, 0, stream>>>(x, qkv_w, qkv, B_ * T_, 3 * D_, D_);
  k_gauss<<<(B_ * T_ * H_ * S_) / 256, 256, 0, stream>>>(qkv, centers, inv_var,
                                                         eff_amps, inv_temp, qw, kw);
  k_stats<<<B_ * H_ * (T_ / ITS), 256, 0, stream>>>(qw, kw, m_g, is_g);
  k_attnw<<<B_ * (T_ / ITW) * 4, 256, 0, stream>>>(qw, kw, m_g, is_g, attn);
  k_pv<<<B_ * H_ * (T_ / PVI), 256, 0, stream>>>(qkv, qw, kw, m_g, is_g, out_pre);
  dim3 g2(512 / 64, 4096 / 64);     // 8 x 64 = 512 WGs
  gemm_t<64, 64><<<g2, 256, 0, stream>>>(out_pre, out_w, out, B_ * T_, D_, D_);
}

// Round 9
// 356.317 us; speedup vs baseline: 1.6319x; 1.0844x over previous
//
#include <hip/hip_runtime.h>
#include <hip/hip_bf16.h>

#define B_ 4
#define T_ 1024
#define D_ 512
#define H_ 8
#define S_ 16
#define HD_ 64
#define ITS 8    // i-rows per WG (stats)
#define ITW 8    // i-rows per WG (attnw)
#define PVI 32   // i-rows per WG (pv)
#define PVJ 64   // j-chunk (pv)

// ---------------- params: centers, inv_var, eff_amps, inv_temp ----------------
__global__ void k_params(const float* __restrict__ base_centers,
                         const float* __restrict__ center_deltas,
                         const float* __restrict__ log_scales,
                         const float* __restrict__ log_amps,
                         const float* __restrict__ movement_param,
                         const float* __restrict__ temperature,
                         float* __restrict__ centers,
                         float* __restrict__ inv_var,
                         float* __restrict__ eff_amps,
                         float* __restrict__ inv_temp) {
  int tid = blockIdx.x * blockDim.x + threadIdx.x;
  float move = (1.f / (1.f + __expf(-movement_param[0]))) * 0.2f;
  for (int i = tid; i < H_ * S_ * HD_; i += blockDim.x * gridDim.x)
    centers[i] = base_centers[i] + center_deltas[i] * move;
  if (tid < H_ * S_) {
    float sc = __expf(log_scales[tid]);
    sc = fminf(fmaxf(sc, 1e-4f), 5.f);
    float am = __expf(log_amps[tid]);
    am = fminf(fmaxf(am, 1e-6f), 10.f);
    inv_var[tid] = 1.f / (sc * sc + 1e-8f);
    eff_amps[tid] = (am > 0.001f) ? am : 0.f;
  }
  if (tid == 0) {
    float t = fminf(fmaxf(temperature[0], 0.01f), 10.f);
    inv_temp[0] = 1.f / t;
  }
}

// ---------------- fp32 GEMM: C[M,N] = A[M,K] @ Bw[N,K]^T, BMxBN tile ----------------
template <int BM, int BN>
__global__ __launch_bounds__(256) void gemm_t(const float* __restrict__ A,
                                              const float* __restrict__ Bw,
                                              float* __restrict__ C,
                                              int M, int N, int K) {
  __shared__ float As[16][BM + 4];
  __shared__ float Bs[16][BN + 4];
  const int tid = threadIdx.x;
  const int m0 = blockIdx.y * BM;
  const int n0 = blockIdx.x * BN;
  const int tx = tid & 15;
  const int ty = tid >> 4;
  constexpr int TM = BM / 16;
  constexpr int TN = BN / 16;
  float acc[TM][TN] = {};
  for (int k0 = 0; k0 < K; k0 += 16) {
#pragma unroll
    for (int l = 0; l < BM / 64; ++l) {
      int idx = (tid + l * 256) * 4;
      int m = idx >> 4, kk = idx & 15;
      float4 v = *(const float4*)(A + (size_t)(m0 + m) * K + k0 + kk);
      As[kk + 0][m] = v.x; As[kk + 1][m] = v.y; As[kk + 2][m] = v.z; As[kk + 3][m] = v.w;
    }
#pragma unroll
    for (int l = 0; l < BN / 64; ++l) {
      int idx = (tid + l * 256) * 4;
      int m = idx >> 4, kk = idx & 15;
      float4 w = *(const float4*)(Bw + (size_t)(n0 + m) * K + k0 + kk);
      Bs[kk + 0][m] = w.x; Bs[kk + 1][m] = w.y; Bs[kk + 2][m] = w.z; Bs[kk + 3][m] = w.w;
    }
    __syncthreads();
#pragma unroll
    for (int kk = 0; kk < 16; ++kk) {
      float av[TM], bv[TN];
#pragma unroll
      for (int u = 0; u < TM / 4; ++u) {
        float4 a = *(const float4*)&As[kk][u * 64 + ty * 4];
        av[u * 4 + 0] = a.x; av[u * 4 + 1] = a.y;
        av[u * 4 + 2] = a.z; av[u * 4 + 3] = a.w;
      }
#pragma unroll
      for (int u = 0; u < TN / 4; ++u) {
        float4 b = *(const float4*)&Bs[kk][u * 64 + tx * 4];
        bv[u * 4 + 0] = b.x; bv[u * 4 + 1] = b.y;
        bv[u * 4 + 2] = b.z; bv[u * 4 + 3] = b.w;
      }
#pragma unroll
      for (int i = 0; i < TM; ++i)
#pragma unroll
        for (int j = 0; j < TN; ++j)
          acc[i][j] += av[i] * bv[j];
    }
    __syncthreads();
  }
#pragma unroll
  for (int i = 0; i < TM; ++i) {
    int row = m0 + (i >> 2) * 64 + ty * 4 + (i & 3);
#pragma unroll
    for (int jc = 0; jc < TN / 4; ++jc) {
      float4 v = make_float4(acc[i][jc * 4 + 0], acc[i][jc * 4 + 1],
                             acc[i][jc * 4 + 2], acc[i][jc * 4 + 3]);
      *(float4*)(C + (size_t)row * N + n0 + jc * 64 + tx * 4) = v;
    }
  }
}

// ---------------- gaussian kernel weights: q_w (× 1/temp), k_w ----------------
__global__ __launch_bounds__(256) void k_gauss(const float* __restrict__ qkv,
                                               const float* __restrict__ centers,
                                               const float* __restrict__ inv_var,
                                               const float* __restrict__ eff_amps,
                                               const float* __restrict__ inv_temp,
                                               float* __restrict__ qw,
                                               float* __restrict__ kw) {
  int gid = blockIdx.x * blockDim.x + threadIdx.x;
  if (gid >= B_ * T_ * H_ * S_) return;
  int s = gid & 15;
  int h = (gid >> 4) & 7;
  int bt = gid >> 7;  // b*T + t
  const float* qrow = qkv + (size_t)bt * 1536 + h * 64;
  const float* krow = qrow + 512;
  const float* c = centers + (h * 16 + s) * 64;
  float qd = 0.f, kd = 0.f;
#pragma unroll
  for (int d = 0; d < 64; d += 4) {
    float4 cv = *(const float4*)(c + d);
    float4 qv = *(const float4*)(qrow + d);
    float4 kv = *(const float4*)(krow + d);
    float t;
    t = qv.x - cv.x; qd += t * t;
    t = qv.y - cv.y; qd += t * t;
    t = qv.z - cv.z; qd += t * t;
    t = qv.w - cv.w; qd += t * t;
    t = kv.x - cv.x; kd += t * t;
    t = kv.y - cv.y; kd += t * t;
    t = kv.z - cv.z; kd += t * t;
    t = kv.w - cv.w; kd += t * t;
  }
  qd = fminf(qd, 100.f);
  kd = fminf(kd, 100.f);
  float iv = inv_var[h * 16 + s];
  float ea = eff_amps[h * 16 + s];
  qw[gid] = __expf(-0.5f * qd * iv) * ea * inv_temp[0];
  kw[gid] = __expf(-0.5f * kd * iv) * ea;
}

__device__ __forceinline__ float dot16(const float4 q[4], const float4 k[4]) {
  return q[0].x * k[0].x + q[0].y * k[0].y + q[0].z * k[0].z + q[0].w * k[0].w +
         q[1].x * k[1].x + q[1].y * k[1].y + q[1].z * k[1].z + q[1].w * k[1].w +
         q[2].x * k[2].x + q[2].y * k[2].y + q[2].z * k[2].z + q[2].w * k[2].w +
         q[3].x * k[3].x + q[3].y * k[3].y + q[3].z * k[3].z + q[3].w * k[3].w;
}

// ---------------- softmax stats: m_i, 1/s_i per (b,h,i) ----------------
__global__ __launch_bounds__(256) void k_stats(const float* __restrict__ qw_g,
                                               const float* __restrict__ kw_g,
                                               float* __restrict__ m_g,
                                               float* __restrict__ is_g) {
  const int x = blockIdx.x;
  const int ic = x & 127;
  const int h = (x >> 7) & 7;
  const int b = x >> 10;
  const int i0 = ic * ITS;
  const int tid = threadIdx.x;

  __shared__ float qw_l[ITS * 16];
  __shared__ float red[4][ITS][2];

  if (tid < 32) {
    int r = tid >> 2, s4 = (tid & 3) * 4;
    *(float4*)&qw_l[r * 16 + s4] =
        *(const float4*)(qw_g + (((size_t)(b * T_ + i0 + r) * H_ + h) * S_ + s4));
  }
  __syncthreads();

  float m[ITS], s[ITS];
#pragma unroll
  for (int r = 0; r < ITS; ++r) { m[r] = -1e30f; s[r] = 0.f; }

  for (int c = 0; c < T_ / 256; ++c) {
    int j = c * 256 + tid;
    const float* kp = kw_g + ((size_t)(b * T_ + j) * H_ + h) * S_;
    float4 k4[4];
    k4[0] = *(const float4*)(kp);
    k4[1] = *(const float4*)(kp + 4);
    k4[2] = *(const float4*)(kp + 8);
    k4[3] = *(const float4*)(kp + 12);
#pragma unroll
    for (int r = 0; r < ITS; ++r) {
      float4 q4[4];
      q4[0] = *(const float4*)&qw_l[r * 16 + 0];
      q4[1] = *(const float4*)&qw_l[r * 16 + 4];
      q4[2] = *(const float4*)&qw_l[r * 16 + 8];
      q4[3] = *(const float4*)&qw_l[r * 16 + 12];
      float l = dot16(q4, k4);
      float mn = fmaxf(m[r], l);
      s[r] = s[r] * __expf(m[r] - mn) + __expf(l - mn);
      m[r] = mn;
    }
  }
#pragma unroll
  for (int o = 1; o < 64; o <<= 1) {
#pragma unroll
    for (int r = 0; r < ITS; ++r) {
      float m2 = __shfl_xor(m[r], o);
      float s2 = __shfl_xor(s[r], o);
      float mn = fmaxf(m[r], m2);
      s[r] = s[r] * __expf(m[r] - mn) + s2 * __expf(m2 - mn);
      m[r] = mn;
    }
  }
  int wv = tid >> 6;
  if ((tid & 63) == 0) {
#pragma unroll
    for (int r = 0; r < ITS; ++r) { red[wv][r][0] = m[r]; red[wv][r][1] = s[r]; }
  }
  __syncthreads();
  if (tid < ITS) {
    float mf = red[0][tid][0], sf = red[0][tid][1];
#pragma unroll
    for (int w = 1; w < 4; ++w) {
      float m2 = red[w][tid][0], s2 = red[w][tid][1];
      float mn = fmaxf(mf, m2);
      sf = sf * __expf(mf - mn) + s2 * __expf(m2 - mn);
      mf = mn;
    }
    size_t o = (size_t)(b * H_ + h) * T_ + i0 + tid;
    m_g[o] = mf;
    is_g[o] = 1.f / sf;
  }
}

// ---------------- attn writer: recompute logits, write attn only ----------------
__global__ __launch_bounds__(256, 4) void k_attnw(const float* __restrict__ qw_g,
                                                  const float* __restrict__ kw_g,
                                                  const float* __restrict__ m_g,
                                                  const float* __restrict__ is_g,
                                                  float* __restrict__ attn) {
  const int x = blockIdx.x;
  const int jt = x & 3;
  const int it = (x >> 2) & 127;
  const int b = x >> 9;
  const int i0 = it * ITW;
  const int jbase = jt * 256;
  const int tid = threadIdx.x;

  __shared__ float qw_l[ITW][H_ * S_];     // 4 KB
  __shared__ float msl[ITW][H_];
  __shared__ float isl[ITW][H_];
  __shared__ float tile[ITW][H_][68];      // 17.4 KB

  {
    int f = tid * 4;
    int r = f >> 7, c = f & 127;
    *(float4*)&qw_l[r][c] = *(const float4*)(qw_g + ((size_t)(b * T_ + i0 + r) * 128 + c));
  }
  if (tid < 64) {
    int r = tid >> 3, hh = tid & 7;
    size_t o = (size_t)(b * H_ + hh) * T_ + i0 + r;
    msl[r][hh] = m_g[o];
    isl[r][hh] = is_g[o];
  }
  __syncthreads();

  const int h = tid >> 5;
  const int jq = tid & 31;
  const float* kw_b = kw_g + (size_t)b * T_ * (H_ * S_);
  float* attn_b = attn + (size_t)(b * T_ + i0) * (T_ * H_);

  for (int st = 0; st < 4; ++st) {
    const int j0 = jbase + st * 64;
    const float* kp = kw_b + ((size_t)(j0 + jq * 2) * H_ + h) * S_;
    float4 ka[4], kb[4];
    ka[0] = *(const float4*)(kp);       ka[1] = *(const float4*)(kp + 4);
    ka[2] = *(const float4*)(kp + 8);   ka[3] = *(const float4*)(kp + 12);
    kb[0] = *(const float4*)(kp + 128); kb[1] = *(const float4*)(kp + 132);
    kb[2] = *(const float4*)(kp + 136); kb[3] = *(const float4*)(kp + 140);
#pragma unroll
    for (int r = 0; r < ITW; ++r) {
      float4 q4[4];
      q4[0] = *(const float4*)&qw_l[r][h * 16 + 0];
      q4[1] = *(const float4*)&qw_l[r][h * 16 + 4];
      q4[2] = *(const float4*)&qw_l[r][h * 16 + 8];
      q4[3] = *(const float4*)&qw_l[r][h * 16 + 12];
      float la = dot16(q4, ka);
      float lb = dot16(q4, kb);
      float mm = msl[r][h], ii = isl[r][h];
      *(float2*)&tile[r][h][jq * 2] =
          make_float2(__expf(la - mm) * ii, __expf(lb - mm) * ii);
    }
    __syncthreads();
#pragma unroll
    for (int l = 0; l < 4; ++l) {
      int f = (l * 256 + tid) * 4;
      int r = f >> 9;
      int rem = f & 511;
      int jl = rem >> 3;
      int h0 = rem & 7;  // 0 or 4
      float4 v;
      v.x = tile[r][h0 + 0][jl];
      v.y = tile[r][h0 + 1][jl];
      v.z = tile[r][h0 + 2][jl];
      v.w = tile[r][h0 + 3][jl];
      *(float4*)(attn_b + (size_t)r * (T_ * H_) + (size_t)(j0 + jl) * H_ + h0) = v;
    }
    __syncthreads();
  }
}

// ---------------- PV as tiled GEMM with P-recompute (v2: LDS-lean) ----------------
// Fixes round-8's LDS saturation: qw/m/is live in REGISTERS (chunk-invariant per
// thread); kw_l rows padded to 20 floats (16B-aligned) so phase-1 reads are b128
// (was ~256 scalar b32/thread/chunk); phase-2 thread tile 4i x 4d (16 FMA per
// 2 b128) with j split across WG halves, merged once at the end via LDS.
__global__ __launch_bounds__(256, 4) void k_pv(const float* __restrict__ qkv,
                                               const float* __restrict__ qw_g,
                                               const float* __restrict__ kw_g,
                                               const float* __restrict__ m_g,
                                               const float* __restrict__ is_g,
                                               float* __restrict__ out_pre) {
  const int bid = blockIdx.x;
  const int xcd = bid & 7;
  const int q = bid >> 3;              // 0..127
  const int p = xcd * 4 + (q & 3);     // panel 0..31
  const int ib = q >> 2;               // 0..31
  const int b = p >> 3;
  const int h = p & 7;
  const int i0 = ib * PVI;
  const int t = threadIdx.x;

  __shared__ float kw_l[PVJ][20];      // 5.1 KB (16B-aligned rows)
  __shared__ float Vl[PVJ][68];        // 17.4 KB
  __shared__ float Pl[PVJ][68];        // 17.4 KB (also merge scratch)

  // ---- registers: qw rows (4 i), m, 1/s (chunk-invariant) ----
  const int jp = (t & 31) * 2;         // phase-1: this thread's 2 j's
  const int iq = t >> 5;               // phase-1: i-quad 0..7
  float qwr[4][16];
  float mreg[4], isr[4];
#pragma unroll
  for (int ii = 0; ii < 4; ++ii) {
    const float* qp = qw_g + (((size_t)(b * T_ + i0 + iq * 4 + ii) * H_ + h) * S_);
#pragma unroll
    for (int s4 = 0; s4 < 4; ++s4) {
      float4 v = *(const float4*)(qp + s4 * 4);
      qwr[ii][s4 * 4 + 0] = v.x; qwr[ii][s4 * 4 + 1] = v.y;
      qwr[ii][s4 * 4 + 2] = v.z; qwr[ii][s4 * 4 + 3] = v.w;
    }
    size_t o = (size_t)(b * H_ + h) * T_ + i0 + iq * 4 + ii;
    mreg[ii] = m_g[o];
    isr[ii] = is_g[o];
  }

  const int half = t >> 7;             // phase-2: j-half
  const int ty = (t >> 4) & 7;         // phase-2: i-quad
  const int tx = t & 15;               // phase-2: d-quad
  float acc[4][4] = {};

  for (int jc = 0; jc < T_ / PVJ; ++jc) {
    const int j0 = jc * PVJ;
    __syncthreads();  // protect LDS from previous-iteration readers
    // stage kw chunk: 64 j x 16 (float4 -> aligned row)
    {
      int j = t >> 2, s4 = (t & 3) * 4;
      float4 v = *(const float4*)(kw_g + (((size_t)(b * T_ + j0 + j) * H_ + h) * S_ + s4));
      *(float4*)&kw_l[j][s4] = v;
    }
    // stage V chunk: 64 j x 64 d
    {
      int j = t >> 4, d4 = (t & 15) * 4;
#pragma unroll
      for (int u = 0; u < 4; ++u) {
        float4 v = *(const float4*)(qkv + (size_t)(b * T_ + j0 + j + u * 16) * 1536 +
                                    1024 + h * 64 + d4);
        *(float4*)&Vl[j + u * 16][d4] = v;
      }
    }
    __syncthreads();
    // phase 1: 2 j's x 4 i's per thread, all-b128, qw from registers
#pragma unroll
    for (int u = 0; u < 2; ++u) {
      int j = jp + u;
      float4 k0 = *(const float4*)&kw_l[j][0];
      float4 k1 = *(const float4*)&kw_l[j][4];
      float4 k2 = *(const float4*)&kw_l[j][8];
      float4 k3 = *(const float4*)&kw_l[j][12];
      float pv[4];
#pragma unroll
      for (int ii = 0; ii < 4; ++ii) {
        float d = qwr[ii][0] * k0.x + qwr[ii][1] * k0.y +
                  qwr[ii][2] * k0.z + qwr[ii][3] * k0.w +
                  qwr[ii][4] * k1.x + qwr[ii][5] * k1.y +
                  qwr[ii][6] * k1.z + qwr[ii][7] * k1.w +
                  qwr[ii][8] * k2.x + qwr[ii][9] * k2.y +
                  qwr[ii][10] * k2.z + qwr[ii][11] * k2.w +
                  qwr[ii][12] * k3.x + qwr[ii][13] * k3.y +
                  qwr[ii][14] * k3.z + qwr[ii][15] * k3.w;
        pv[ii] = __expf(d - mreg[ii]) * isr[ii];
      }
      *(float4*)&Pl[j][iq * 4] = make_float4(pv[0], pv[1], pv[2], pv[3]);
    }
    __syncthreads();
    // phase 2: my half's 32 j; 16 FMA per 2 b128
#pragma unroll 8
    for (int jj = 0; jj < PVJ / 2; ++jj) {
      int j = half * (PVJ / 2) + jj;
      float4 pp = *(const float4*)&Pl[j][ty * 4];
      float4 vv = *(const float4*)&Vl[j][tx * 4];
      acc[0][0] += pp.x * vv.x; acc[0][1] += pp.x * vv.y;
      acc[0][2] += pp.x * vv.z; acc[0][3] += pp.x * vv.w;
      acc[1][0] += pp.y * vv.x; acc[1][1] += pp.y * vv.y;
      acc[1][2] += pp.y * vv.z; acc[1][3] += pp.y * vv.w;
      acc[2][0] += pp.z * vv.x; acc[2][1] += pp.z * vv.y;
      acc[2][2] += pp.z * vv.z; acc[2][3] += pp.z * vv.w;
      acc[3][0] += pp.w * vv.x; acc[3][1] += pp.w * vv.y;
      acc[3][2] += pp.w * vv.z; acc[3][3] += pp.w * vv.w;
    }
  }
  // merge the two j-halves (scratch = Pl, stride 20 floats to spread banks)
  __syncthreads();
  float* mg = &Pl[0][0];
  if (half == 1) {
    float* dst = mg + (size_t)(t - 128) * 20;
#pragma unroll
    for (int ii = 0; ii < 4; ++ii)
      *(float4*)(dst + ii * 4) =
          make_float4(acc[ii][0], acc[ii][1], acc[ii][2], acc[ii][3]);
  }
  __syncthreads();
  if (half == 0) {
    const float* src = mg + (size_t)t * 20;
#pragma unroll
    for (int ii = 0; ii < 4; ++ii) {
      float4 o = *(const float4*)(src + ii * 4);
      o.x += acc[ii][0]; o.y += acc[ii][1]; o.z += acc[ii][2]; o.w += acc[ii][3];
      *(float4*)(out_pre + (size_t)(b * T_ + i0 + ty * 4 + ii) * D_ + h * HD_ + tx * 4) = o;
    }
  }
}

extern "C" void kernel_launch(void* const* d_in, const int* in_sizes, int n_in,
                              void* d_out, int out_size, void* d_ws, size_t ws_size,
                              hipStream_t stream) {
  const float* x = (const float*)d_in[0];
  const float* qkv_w = (const float*)d_in[1];
  const float* out_w = (const float*)d_in[2];
  const float* base_c = (const float*)d_in[3];
  const float* deltas = (const float*)d_in[4];
  const float* log_sc = (const float*)d_in[5];
  const float* log_am = (const float*)d_in[6];
  const float* move_p = (const float*)d_in[7];
  const float* temp = (const float*)d_in[8];

  float* out = (float*)d_out;                    // B*T*D
  float* attn = out + (size_t)B_ * T_ * D_;      // B*T*T*H

  float* ws = (float*)d_ws;
  float* qkv = ws;                                          // 6,291,456
  float* qw = qkv + (size_t)B_ * T_ * 3 * D_;               // 524,288
  float* kw = qw + (size_t)B_ * T_ * H_ * S_;               // 524,288
  float* out_pre = kw + (size_t)B_ * T_ * H_ * S_;          // 2,097,152
  float* centers = out_pre + (size_t)B_ * T_ * D_;          // 8,192
  float* inv_var = centers + H_ * S_ * HD_;                 // 128
  float* eff_amps = inv_var + H_ * S_;                      // 128
  float* inv_temp = eff_amps + H_ * S_;                     // 4 (padded)
  float* m_g = inv_temp + 4;                                // 32,768
  float* is_g = m_g + (size_t)B_ * H_ * T_;                 // 32,768

  k_params<<<32, 256, 0, stream>>>(base_c, deltas, log_sc, log_am, move_p, temp,
                                   centers, inv_var, eff_amps, inv_temp);
  dim3 g1(1536 / 64, 4096 / 128);   // 24 x 32 = 768 WGs
  gemm_t<128, 64><<<g1, 256, 0, stream>>>(x, qkv_w, qkv, B_ * T_, 3 * D_, D_);
  k_gauss<<<(B_ * T_ * H_ * S_) / 256, 256, 0, stream>>>(qkv, centers, inv_var,
                                                         eff_amps, inv_temp, qw, kw);
  k_stats<<<B_ * H_ * (T_ / ITS), 256, 0, stream>>>(qw, kw, m_g, is_g);
  k_attnw<<<B_ * (T_ / ITW) * 4, 256, 0, stream>>>(qw, kw, m_g, is_g, attn);
  k_pv<<<B_ * H_ * (T_ / PVI), 256, 0, stream>>>(qkv, qw, kw, m_g, is_g, out_pre);
  dim3 g2(512 / 64, 4096 / 64);     // 8 x 64 = 512 WGs
  gemm_t<64, 64><<<g2, 256, 0, stream>>>(out_pre, out_w, out, B_ * T_, D_, D_);
}

// Round 10
// 356.055 us; speedup vs baseline: 1.6331x; 1.0007x over previous
//
#include <hip/hip_runtime.h>
#include <hip/hip_bf16.h>

#define B_ 4
#define T_ 1024
#define D_ 512
#define H_ 8
#define S_ 16
#define HD_ 64
#define ITS 8    // i-rows per WG (stats)
#define ITW 8    // i-rows per WG (attnw)
#define PVI 32   // i-rows per WG (pv)
#define PVJ 64   // j-chunk (pv)

typedef short bf16x8 __attribute__((ext_vector_type(8)));
typedef float f32x4m __attribute__((ext_vector_type(4)));

__device__ __forceinline__ unsigned short f2bf(float f) {
  unsigned u = __float_as_uint(f);
  unsigned r = (u + 0x7FFFu + ((u >> 16) & 1u)) >> 16;  // RNE
  return (unsigned short)r;
}
__device__ __forceinline__ float bf2f(unsigned short h) {
  return __uint_as_float((unsigned)h << 16);
}

// ---------------- params: centers, inv_var, eff_amps, inv_temp ----------------
__global__ void k_params(const float* __restrict__ base_centers,
                         const float* __restrict__ center_deltas,
                         const float* __restrict__ log_scales,
                         const float* __restrict__ log_amps,
                         const float* __restrict__ movement_param,
                         const float* __restrict__ temperature,
                         float* __restrict__ centers,
                         float* __restrict__ inv_var,
                         float* __restrict__ eff_amps,
                         float* __restrict__ inv_temp) {
  int tid = blockIdx.x * blockDim.x + threadIdx.x;
  float move = (1.f / (1.f + __expf(-movement_param[0]))) * 0.2f;
  for (int i = tid; i < H_ * S_ * HD_; i += blockDim.x * gridDim.x)
    centers[i] = base_centers[i] + center_deltas[i] * move;
  if (tid < H_ * S_) {
    float sc = __expf(log_scales[tid]);
    sc = fminf(fmaxf(sc, 1e-4f), 5.f);
    float am = __expf(log_amps[tid]);
    am = fminf(fmaxf(am, 1e-6f), 10.f);
    inv_var[tid] = 1.f / (sc * sc + 1e-8f);
    eff_amps[tid] = (am > 0.001f) ? am : 0.f;
  }
  if (tid == 0) {
    float t = fminf(fmaxf(temperature[0], 0.01f), 10.f);
    inv_temp[0] = 1.f / t;
  }
}

// ---------------- split fp32 -> (hi, lo) bf16 pair ----------------
__global__ __launch_bounds__(256) void k_split(const float* __restrict__ src,
                                               unsigned short* __restrict__ hi,
                                               unsigned short* __restrict__ lo,
                                               int n4) {
  int i = blockIdx.x * blockDim.x + threadIdx.x;
  if (i >= n4) return;
  float4 v = ((const float4*)src)[i];
  ushort4 h, l;
  h.x = f2bf(v.x); l.x = f2bf(v.x - bf2f(h.x));
  h.y = f2bf(v.y); l.y = f2bf(v.y - bf2f(h.y));
  h.z = f2bf(v.z); l.z = f2bf(v.z - bf2f(h.z));
  h.w = f2bf(v.w); l.w = f2bf(v.w - bf2f(h.w));
  ((ushort4*)hi)[i] = h;
  ((ushort4*)lo)[i] = l;
}

// ---------------- split-bf16 MFMA GEMM: C[M,N] = A[M,K] @ Bw[N,K]^T ----------------
// 3-product split: C ~= Ah@Bh + Ah@Bl + Al@Bh (err ~2^-18 rel).
// LDS-free: frags loaded per-lane from global (L2-served), reuse in registers.
// Layout (guide-verified m89/m91): A/B frag: lane&15 = m|n, k=(lane>>4)*8+j
// (8 contiguous bf16 = one 16B load); D: col=lane&15, row=(lane>>4)*4+reg.
template <int BN>
__global__ __launch_bounds__(256) void gemm_mfma(const unsigned short* __restrict__ Ah,
                                                 const unsigned short* __restrict__ Al,
                                                 const unsigned short* __restrict__ Bh,
                                                 const unsigned short* __restrict__ Bl,
                                                 float* __restrict__ C,
                                                 int M, int N, int K) {
  constexpr int NF = BN / 16;
  const int t = threadIdx.x;
  const int lane = t & 63;
  const int wv = t >> 6;
  const int m0 = blockIdx.y * 128 + wv * 32;  // 4 waves stacked in M
  const int n0 = blockIdx.x * BN;
  const int lr = lane & 15;
  const int kg = lane >> 4;

  const unsigned short* a0h = Ah + (size_t)(m0 + lr) * K + kg * 8;
  const unsigned short* a1h = a0h + (size_t)16 * K;
  const unsigned short* a0l = Al + (size_t)(m0 + lr) * K + kg * 8;
  const unsigned short* a1l = a0l + (size_t)16 * K;
  const unsigned short* bph = Bh + (size_t)(n0 + lr) * K + kg * 8;
  const unsigned short* bpl = Bl + (size_t)(n0 + lr) * K + kg * 8;

  f32x4m acc[2][NF];
#pragma unroll
  for (int i = 0; i < 2; ++i)
#pragma unroll
    for (int f = 0; f < NF; ++f) {
      f32x4m z = {0.f, 0.f, 0.f, 0.f};
      acc[i][f] = z;
    }

  for (int k0 = 0; k0 < K; k0 += 32) {
    bf16x8 ah0 = *(const bf16x8*)(a0h + k0);
    bf16x8 ah1 = *(const bf16x8*)(a1h + k0);
    bf16x8 al0 = *(const bf16x8*)(a0l + k0);
    bf16x8 al1 = *(const bf16x8*)(a1l + k0);
#pragma unroll
    for (int f = 0; f < NF; ++f) {
      bf16x8 vbh = *(const bf16x8*)(bph + (size_t)f * 16 * K + k0);
      bf16x8 vbl = *(const bf16x8*)(bpl + (size_t)f * 16 * K + k0);
      acc[0][f] = __builtin_amdgcn_mfma_f32_16x16x32_bf16(al0, vbh, acc[0][f], 0, 0, 0);
      acc[0][f] = __builtin_amdgcn_mfma_f32_16x16x32_bf16(ah0, vbl, acc[0][f], 0, 0, 0);
      acc[0][f] = __builtin_amdgcn_mfma_f32_16x16x32_bf16(ah0, vbh, acc[0][f], 0, 0, 0);
      acc[1][f] = __builtin_amdgcn_mfma_f32_16x16x32_bf16(al1, vbh, acc[1][f], 0, 0, 0);
      acc[1][f] = __builtin_amdgcn_mfma_f32_16x16x32_bf16(ah1, vbl, acc[1][f], 0, 0, 0);
      acc[1][f] = __builtin_amdgcn_mfma_f32_16x16x32_bf16(ah1, vbh, acc[1][f], 0, 0, 0);
    }
  }
#pragma unroll
  for (int i = 0; i < 2; ++i)
#pragma unroll
    for (int f = 0; f < NF; ++f)
#pragma unroll
      for (int r = 0; r < 4; ++r)
        C[(size_t)(m0 + i * 16 + kg * 4 + r) * N + n0 + f * 16 + lr] = acc[i][f][r];
}

// ---------------- gaussian kernel weights: q_w (× 1/temp), k_w ----------------
__global__ __launch_bounds__(256) void k_gauss(const float* __restrict__ qkv,
                                               const float* __restrict__ centers,
                                               const float* __restrict__ inv_var,
                                               const float* __restrict__ eff_amps,
                                               const float* __restrict__ inv_temp,
                                               float* __restrict__ qw,
                                               float* __restrict__ kw) {
  int gid = blockIdx.x * blockDim.x + threadIdx.x;
  if (gid >= B_ * T_ * H_ * S_) return;
  int s = gid & 15;
  int h = (gid >> 4) & 7;
  int bt = gid >> 7;  // b*T + t
  const float* qrow = qkv + (size_t)bt * 1536 + h * 64;
  const float* krow = qrow + 512;
  const float* c = centers + (h * 16 + s) * 64;
  float qd = 0.f, kd = 0.f;
#pragma unroll
  for (int d = 0; d < 64; d += 4) {
    float4 cv = *(const float4*)(c + d);
    float4 qv = *(const float4*)(qrow + d);
    float4 kv = *(const float4*)(krow + d);
    float t;
    t = qv.x - cv.x; qd += t * t;
    t = qv.y - cv.y; qd += t * t;
    t = qv.z - cv.z; qd += t * t;
    t = qv.w - cv.w; qd += t * t;
    t = kv.x - cv.x; kd += t * t;
    t = kv.y - cv.y; kd += t * t;
    t = kv.z - cv.z; kd += t * t;
    t = kv.w - cv.w; kd += t * t;
  }
  qd = fminf(qd, 100.f);
  kd = fminf(kd, 100.f);
  float iv = inv_var[h * 16 + s];
  float ea = eff_amps[h * 16 + s];
  qw[gid] = __expf(-0.5f * qd * iv) * ea * inv_temp[0];
  kw[gid] = __expf(-0.5f * kd * iv) * ea;
}

__device__ __forceinline__ float dot16(const float4 q[4], const float4 k[4]) {
  return q[0].x * k[0].x + q[0].y * k[0].y + q[0].z * k[0].z + q[0].w * k[0].w +
         q[1].x * k[1].x + q[1].y * k[1].y + q[1].z * k[1].z + q[1].w * k[1].w +
         q[2].x * k[2].x + q[2].y * k[2].y + q[2].z * k[2].z + q[2].w * k[2].w +
         q[3].x * k[3].x + q[3].y * k[3].y + q[3].z * k[3].z + q[3].w * k[3].w;
}

// ---------------- softmax stats: m_i, 1/s_i per (b,h,i) ----------------
__global__ __launch_bounds__(256) void k_stats(const float* __restrict__ qw_g,
                                               const float* __restrict__ kw_g,
                                               float* __restrict__ m_g,
                                               float* __restrict__ is_g) {
  const int x = blockIdx.x;
  const int ic = x & 127;
  const int h = (x >> 7) & 7;
  const int b = x >> 10;
  const int i0 = ic * ITS;
  const int tid = threadIdx.x;

  __shared__ float qw_l[ITS * 16];
  __shared__ float red[4][ITS][2];

  if (tid < 32) {
    int r = tid >> 2, s4 = (tid & 3) * 4;
    *(float4*)&qw_l[r * 16 + s4] =
        *(const float4*)(qw_g + (((size_t)(b * T_ + i0 + r) * H_ + h) * S_ + s4));
  }
  __syncthreads();

  float m[ITS], s[ITS];
#pragma unroll
  for (int r = 0; r < ITS; ++r) { m[r] = -1e30f; s[r] = 0.f; }

  for (int c = 0; c < T_ / 256; ++c) {
    int j = c * 256 + tid;
    const float* kp = kw_g + ((size_t)(b * T_ + j) * H_ + h) * S_;
    float4 k4[4];
    k4[0] = *(const float4*)(kp);
    k4[1] = *(const float4*)(kp + 4);
    k4[2] = *(const float4*)(kp + 8);
    k4[3] = *(const float4*)(kp + 12);
#pragma unroll
    for (int r = 0; r < ITS; ++r) {
      float4 q4[4];
      q4[0] = *(const float4*)&qw_l[r * 16 + 0];
      q4[1] = *(const float4*)&qw_l[r * 16 + 4];
      q4[2] = *(const float4*)&qw_l[r * 16 + 8];
      q4[3] = *(const float4*)&qw_l[r * 16 + 12];
      float l = dot16(q4, k4);
      float mn = fmaxf(m[r], l);
      s[r] = s[r] * __expf(m[r] - mn) + __expf(l - mn);
      m[r] = mn;
    }
  }
#pragma unroll
  for (int o = 1; o < 64; o <<= 1) {
#pragma unroll
    for (int r = 0; r < ITS; ++r) {
      float m2 = __shfl_xor(m[r], o);
      float s2 = __shfl_xor(s[r], o);
      float mn = fmaxf(m[r], m2);
      s[r] = s[r] * __expf(m[r] - mn) + s2 * __expf(m2 - mn);
      m[r] = mn;
    }
  }
  int wv = tid >> 6;
  if ((tid & 63) == 0) {
#pragma unroll
    for (int r = 0; r < ITS; ++r) { red[wv][r][0] = m[r]; red[wv][r][1] = s[r]; }
  }
  __syncthreads();
  if (tid < ITS) {
    float mf = red[0][tid][0], sf = red[0][tid][1];
#pragma unroll
    for (int w = 1; w < 4; ++w) {
      float m2 = red[w][tid][0], s2 = red[w][tid][1];
      float mn = fmaxf(mf, m2);
      sf = sf * __expf(mf - mn) + s2 * __expf(m2 - mn);
      mf = mn;
    }
    size_t o = (size_t)(b * H_ + h) * T_ + i0 + tid;
    m_g[o] = mf;
    is_g[o] = 1.f / sf;
  }
}

// ---------------- attn writer: recompute logits, write attn only ----------------
__global__ __launch_bounds__(256, 4) void k_attnw(const float* __restrict__ qw_g,
                                                  const float* __restrict__ kw_g,
                                                  const float* __restrict__ m_g,
                                                  const float* __restrict__ is_g,
                                                  float* __restrict__ attn) {
  const int x = blockIdx.x;
  const int jt = x & 3;
  const int it = (x >> 2) & 127;
  const int b = x >> 9;
  const int i0 = it * ITW;
  const int jbase = jt * 256;
  const int tid = threadIdx.x;

  __shared__ float qw_l[ITW][H_ * S_];     // 4 KB
  __shared__ float msl[ITW][H_];
  __shared__ float isl[ITW][H_];
  __shared__ float tile[ITW][H_][68];      // 17.4 KB

  {
    int f = tid * 4;
    int r = f >> 7, c = f & 127;
    *(float4*)&qw_l[r][c] = *(const float4*)(qw_g + ((size_t)(b * T_ + i0 + r) * 128 + c));
  }
  if (tid < 64) {
    int r = tid >> 3, hh = tid & 7;
    size_t o = (size_t)(b * H_ + hh) * T_ + i0 + r;
    msl[r][hh] = m_g[o];
    isl[r][hh] = is_g[o];
  }
  __syncthreads();

  const int h = tid >> 5;
  const int jq = tid & 31;
  const float* kw_b = kw_g + (size_t)b * T_ * (H_ * S_);
  float* attn_b = attn + (size_t)(b * T_ + i0) * (T_ * H_);

  for (int st = 0; st < 4; ++st) {
    const int j0 = jbase + st * 64;
    const float* kp = kw_b + ((size_t)(j0 + jq * 2) * H_ + h) * S_;
    float4 ka[4], kb[4];
    ka[0] = *(const float4*)(kp);       ka[1] = *(const float4*)(kp + 4);
    ka[2] = *(const float4*)(kp + 8);   ka[3] = *(const float4*)(kp + 12);
    kb[0] = *(const float4*)(kp + 128); kb[1] = *(const float4*)(kp + 132);
    kb[2] = *(const float4*)(kp + 136); kb[3] = *(const float4*)(kp + 140);
#pragma unroll
    for (int r = 0; r < ITW; ++r) {
      float4 q4[4];
      q4[0] = *(const float4*)&qw_l[r][h * 16 + 0];
      q4[1] = *(const float4*)&qw_l[r][h * 16 + 4];
      q4[2] = *(const float4*)&qw_l[r][h * 16 + 8];
      q4[3] = *(const float4*)&qw_l[r][h * 16 + 12];
      float la = dot16(q4, ka);
      float lb = dot16(q4, kb);
      float mm = msl[r][h], ii = isl[r][h];
      *(float2*)&tile[r][h][jq * 2] =
          make_float2(__expf(la - mm) * ii, __expf(lb - mm) * ii);
    }
    __syncthreads();
#pragma unroll
    for (int l = 0; l < 4; ++l) {
      int f = (l * 256 + tid) * 4;
      int r = f >> 9;
      int rem = f & 511;
      int jl = rem >> 3;
      int h0 = rem & 7;  // 0 or 4
      float4 v;
      v.x = tile[r][h0 + 0][jl];
      v.y = tile[r][h0 + 1][jl];
      v.z = tile[r][h0 + 2][jl];
      v.w = tile[r][h0 + 3][jl];
      *(float4*)(attn_b + (size_t)r * (T_ * H_) + (size_t)(j0 + jl) * H_ + h0) = v;
    }
    __syncthreads();
  }
}

// ---------------- PV as tiled GEMM with P-recompute (v3: conflict-free LDS) ----------------
// Round-9 had 3.67M bank conflicts: kw_l[64][20] even-j b128 reads (8-way) and
// Pl stride-68 f4 writes (8 lanes/quad). Fix: kw stored TRANSPOSED kw_t[16][66]
// (scalar reads, 2 lanes/bank = free); Pl[64][32] with quad-XOR swizzle
// quad ^= ((j>>1)^j)&7 -> writes hit all 8 quads uniformly (exact bank floor),
// reads stay broadcast. Output stored as bf16 hi/lo pair for the MFMA out-proj.
__global__ __launch_bounds__(256, 4) void k_pv(const float* __restrict__ qkv,
                                               const float* __restrict__ qw_g,
                                               const float* __restrict__ kw_g,
                                               const float* __restrict__ m_g,
                                               const float* __restrict__ is_g,
                                               unsigned short* __restrict__ oph,
                                               unsigned short* __restrict__ opl) {
  const int bid = blockIdx.x;
  const int xcd = bid & 7;
  const int q = bid >> 3;              // 0..127
  const int p = xcd * 4 + (q & 3);     // panel 0..31
  const int ib = q >> 2;               // 0..31
  const int b = p >> 3;
  const int h = p & 7;
  const int i0 = ib * PVI;
  const int t = threadIdx.x;

  __shared__ float kw_t[16][66];       // 4.2 KB, transposed
  __shared__ float Vl[PVJ][68];        // 17.4 KB (also merge scratch at end)
  __shared__ float Pl[PVJ][32];        // 8 KB, quad-XOR swizzled

  // ---- registers: qw rows (4 i), m, 1/s (chunk-invariant) ----
  const int jp = (t & 31) * 2;         // phase-1: this thread's 2 j's
  const int iq = t >> 5;               // phase-1: i-quad 0..7
  float qwr[4][16];
  float mreg[4], isr[4];
#pragma unroll
  for (int ii = 0; ii < 4; ++ii) {
    const float* qp = qw_g + (((size_t)(b * T_ + i0 + iq * 4 + ii) * H_ + h) * S_);
#pragma unroll
    for (int s4 = 0; s4 < 4; ++s4) {
      float4 v = *(const float4*)(qp + s4 * 4);
      qwr[ii][s4 * 4 + 0] = v.x; qwr[ii][s4 * 4 + 1] = v.y;
      qwr[ii][s4 * 4 + 2] = v.z; qwr[ii][s4 * 4 + 3] = v.w;
    }
    size_t o = (size_t)(b * H_ + h) * T_ + i0 + iq * 4 + ii;
    mreg[ii] = m_g[o];
    isr[ii] = is_g[o];
  }

  const int half = t >> 7;             // phase-2: j-half
  const int ty = (t >> 4) & 7;         // phase-2: i-quad
  const int tx = t & 15;               // phase-2: d-quad
  float acc[4][4] = {};

  for (int jc = 0; jc < T_ / PVJ; ++jc) {
    const int j0 = jc * PVJ;
    __syncthreads();  // protect LDS from previous-iteration readers
    // stage kw chunk transposed: kw_t[s][j]
    {
      int j = t >> 2, s4 = (t & 3) * 4;
      float4 v = *(const float4*)(kw_g + (((size_t)(b * T_ + j0 + j) * H_ + h) * S_ + s4));
      kw_t[s4 + 0][j] = v.x; kw_t[s4 + 1][j] = v.y;
      kw_t[s4 + 2][j] = v.z; kw_t[s4 + 3][j] = v.w;
    }
    // stage V chunk: 64 j x 64 d
    {
      int j = t >> 4, d4 = (t & 15) * 4;
#pragma unroll
      for (int u = 0; u < 4; ++u) {
        float4 v = *(const float4*)(qkv + (size_t)(b * T_ + j0 + j + u * 16) * 1536 +
                                    1024 + h * 64 + d4);
        *(float4*)&Vl[j + u * 16][d4] = v;
      }
    }
    __syncthreads();
    // phase 1: 2 j's x 4 i's per thread; kw scalar reads (2-way free), qw in regs
#pragma unroll
    for (int u = 0; u < 2; ++u) {
      int j = jp + u;
      float kj[16];
#pragma unroll
      for (int s = 0; s < 16; ++s) kj[s] = kw_t[s][j];
      float pv[4];
#pragma unroll
      for (int ii = 0; ii < 4; ++ii) {
        float d = 0.f;
#pragma unroll
        for (int s = 0; s < 16; ++s) d += qwr[ii][s] * kj[s];
        pv[ii] = __expf(d - mreg[ii]) * isr[ii];
      }
      int sw = ((j >> 1) ^ j) & 7;
      *(float4*)&Pl[j][((iq ^ sw) & 7) * 4] = make_float4(pv[0], pv[1], pv[2], pv[3]);
    }
    __syncthreads();
    // phase 2: my half's 32 j; P read broadcast (swizzle-aware), V b128
#pragma unroll 8
    for (int jj = 0; jj < PVJ / 2; ++jj) {
      int j = half * (PVJ / 2) + jj;
      int sw = ((j >> 1) ^ j) & 7;
      float4 pp = *(const float4*)&Pl[j][((ty ^ sw) & 7) * 4];
      float4 vv = *(const float4*)&Vl[j][tx * 4];
      acc[0][0] += pp.x * vv.x; acc[0][1] += pp.x * vv.y;
      acc[0][2] += pp.x * vv.z; acc[0][3] += pp.x * vv.w;
      acc[1][0] += pp.y * vv.x; acc[1][1] += pp.y * vv.y;
      acc[1][2] += pp.y * vv.z; acc[1][3] += pp.y * vv.w;
      acc[2][0] += pp.z * vv.x; acc[2][1] += pp.z * vv.y;
      acc[2][2] += pp.z * vv.z; acc[2][3] += pp.z * vv.w;
      acc[3][0] += pp.w * vv.x; acc[3][1] += pp.w * vv.y;
      acc[3][2] += pp.w * vv.z; acc[3][3] += pp.w * vv.w;
    }
  }
  // merge halves via Vl scratch (stride 17 words: 2 lanes/bank = free)
  __syncthreads();
  float* mg = &Vl[0][0];
  if (half == 1) {
    float* dst = mg + (size_t)(t - 128) * 17;
#pragma unroll
    for (int ii = 0; ii < 4; ++ii) {
      dst[ii * 4 + 0] = acc[ii][0]; dst[ii * 4 + 1] = acc[ii][1];
      dst[ii * 4 + 2] = acc[ii][2]; dst[ii * 4 + 3] = acc[ii][3];
    }
  }
  __syncthreads();
  if (half == 0) {
    const float* src = mg + (size_t)t * 17;
#pragma unroll
    for (int ii = 0; ii < 4; ++ii) {
      float4 o;
      o.x = acc[ii][0] + src[ii * 4 + 0];
      o.y = acc[ii][1] + src[ii * 4 + 1];
      o.z = acc[ii][2] + src[ii * 4 + 2];
      o.w = acc[ii][3] + src[ii * 4 + 3];
      ushort4 hv, lv;
      hv.x = f2bf(o.x); lv.x = f2bf(o.x - bf2f(hv.x));
      hv.y = f2bf(o.y); lv.y = f2bf(o.y - bf2f(hv.y));
      hv.z = f2bf(o.z); lv.z = f2bf(o.z - bf2f(hv.z));
      hv.w = f2bf(o.w); lv.w = f2bf(o.w - bf2f(hv.w));
      size_t idx = (size_t)(b * T_ + i0 + ty * 4 + ii) * D_ + h * HD_ + tx * 4;
      *(ushort4*)(oph + idx) = hv;
      *(ushort4*)(opl + idx) = lv;
    }
  }
}

extern "C" void kernel_launch(void* const* d_in, const int* in_sizes, int n_in,
                              void* d_out, int out_size, void* d_ws, size_t ws_size,
                              hipStream_t stream) {
  const float* x = (const float*)d_in[0];
  const float* qkv_w = (const float*)d_in[1];
  const float* out_w = (const float*)d_in[2];
  const float* base_c = (const float*)d_in[3];
  const float* deltas = (const float*)d_in[4];
  const float* log_sc = (const float*)d_in[5];
  const float* log_am = (const float*)d_in[6];
  const float* move_p = (const float*)d_in[7];
  const float* temp = (const float*)d_in[8];

  float* out = (float*)d_out;                    // B*T*D
  float* attn = out + (size_t)B_ * T_ * D_;      // B*T*T*H

  float* ws = (float*)d_ws;
  float* qkv = ws;                                          // 6,291,456 f
  float* qw = qkv + 6291456;                                // 524,288
  float* kw = qw + 524288;                                  // 524,288
  float* centers = kw + 524288;                             // 8,192
  float* inv_var = centers + 8192;                          // 128
  float* eff_amps = inv_var + 128;                          // 128
  float* inv_temp = eff_amps + 128;                         // 4
  float* m_g = inv_temp + 4;                                // 32,768
  float* is_g = m_g + 32768;                                // 32,768
  unsigned short* xh = (unsigned short*)(is_g + 32768);     // 2,097,152 us
  unsigned short* xl = xh + 2097152;                        // 2,097,152
  unsigned short* wh = xl + 2097152;                        // 786,432
  unsigned short* wl = wh + 786432;                         // 786,432
  unsigned short* owh = wl + 786432;                        // 262,144
  unsigned short* owl = owh + 262144;                       // 262,144
  unsigned short* oph = owl + 262144;                       // 2,097,152
  unsigned short* opl = oph + 2097152;                      // 2,097,152

  k_params<<<32, 256, 0, stream>>>(base_c, deltas, log_sc, log_am, move_p, temp,
                                   centers, inv_var, eff_amps, inv_temp);
  k_split<<<2048, 256, 0, stream>>>(x, xh, xl, 2097152 / 4);
  k_split<<<768, 256, 0, stream>>>(qkv_w, wh, wl, 786432 / 4);
  k_split<<<256, 256, 0, stream>>>(out_w, owh, owl, 262144 / 4);

  dim3 g1(1536 / 64, 4096 / 128);   // 24 x 32 = 768 WGs
  gemm_mfma<64><<<g1, 256, 0, stream>>>(xh, xl, wh, wl, qkv, B_ * T_, 3 * D_, D_);

  k_gauss<<<(B_ * T_ * H_ * S_) / 256, 256, 0, stream>>>(qkv, centers, inv_var,
                                                         eff_amps, inv_temp, qw, kw);
  k_stats<<<B_ * H_ * (T_ / ITS), 256, 0, stream>>>(qw, kw, m_g, is_g);
  k_attnw<<<B_ * (T_ / ITW) * 4, 256, 0, stream>>>(qw, kw, m_g, is_g, attn);
  k_pv<<<B_ * H_ * (T_ / PVI), 256, 0, stream>>>(qkv, qw, kw, m_g, is_g, oph, opl);

  dim3 g2(512 / 64, 4096 / 128);    // 8 x 32 = 256 WGs
  gemm_mfma<64><<<g2, 256, 0, stream>>>(oph, opl, owh, owl, out, B_ * T_, D_, D_);
}

// Round 11
// 310.154 us; speedup vs baseline: 1.8748x; 1.1480x over previous
//
#include <hip/hip_runtime.h>
#include <hip/hip_bf16.h>

#define B_ 4
#define T_ 1024
#define D_ 512
#define H_ 8
#define S_ 16
#define HD_ 64
#define ITS 8    // i-rows per WG (stats)
#define ITW 8    // i-rows per WG (attnw)
#define PVI 32   // i-rows per WG (pv)
#define PVJ 64   // j-chunk (pv)

typedef short bf16x8 __attribute__((ext_vector_type(8)));
typedef float f32x4m __attribute__((ext_vector_type(4)));

__device__ __forceinline__ unsigned short f2bf(float f) {
  unsigned u = __float_as_uint(f);
  unsigned r = (u + 0x7FFFu + ((u >> 16) & 1u)) >> 16;  // RNE
  return (unsigned short)r;
}
__device__ __forceinline__ float bf2f(unsigned short h) {
  return __uint_as_float((unsigned)h << 16);
}
// pack 2 f32 -> 2 bf16 in one u32 (elem0 = low 16 = f0)
__device__ __forceinline__ unsigned cvt_pk_bf16(float f0, float f1) {
  unsigned r;
  asm volatile("v_cvt_pk_bf16_f32 %0, %1, %2" : "=v"(r) : "v"(f0), "v"(f1));
  return r;
}
// hi/lo bf16 split of a pair
__device__ __forceinline__ void split2(float f0, float f1, unsigned& hp, unsigned& lp) {
  unsigned hh = cvt_pk_bf16(f0, f1);
  float r0 = __uint_as_float(hh << 16);
  float r1 = __uint_as_float(hh & 0xFFFF0000u);
  lp = cvt_pk_bf16(f0 - r0, f1 - r1);
  hp = hh;
}

// ---------------- params: centers, inv_var, eff_amps, inv_temp ----------------
__global__ void k_params(const float* __restrict__ base_centers,
                         const float* __restrict__ center_deltas,
                         const float* __restrict__ log_scales,
                         const float* __restrict__ log_amps,
                         const float* __restrict__ movement_param,
                         const float* __restrict__ temperature,
                         float* __restrict__ centers,
                         float* __restrict__ inv_var,
                         float* __restrict__ eff_amps,
                         float* __restrict__ inv_temp) {
  int tid = blockIdx.x * blockDim.x + threadIdx.x;
  float move = (1.f / (1.f + __expf(-movement_param[0]))) * 0.2f;
  for (int i = tid; i < H_ * S_ * HD_; i += blockDim.x * gridDim.x)
    centers[i] = base_centers[i] + center_deltas[i] * move;
  if (tid < H_ * S_) {
    float sc = __expf(log_scales[tid]);
    sc = fminf(fmaxf(sc, 1e-4f), 5.f);
    float am = __expf(log_amps[tid]);
    am = fminf(fmaxf(am, 1e-6f), 10.f);
    inv_var[tid] = 1.f / (sc * sc + 1e-8f);
    eff_amps[tid] = (am > 0.001f) ? am : 0.f;
  }
  if (tid == 0) {
    float t = fminf(fmaxf(temperature[0], 0.01f), 10.f);
    inv_temp[0] = 1.f / t;
  }
}

// ---------------- split fp32 -> (hi, lo) bf16 pair ----------------
__global__ __launch_bounds__(256) void k_split(const float* __restrict__ src,
                                               unsigned short* __restrict__ hi,
                                               unsigned short* __restrict__ lo,
                                               int n4) {
  int i = blockIdx.x * blockDim.x + threadIdx.x;
  if (i >= n4) return;
  float4 v = ((const float4*)src)[i];
  ushort4 h, l;
  h.x = f2bf(v.x); l.x = f2bf(v.x - bf2f(h.x));
  h.y = f2bf(v.y); l.y = f2bf(v.y - bf2f(h.y));
  h.z = f2bf(v.z); l.z = f2bf(v.z - bf2f(h.z));
  h.w = f2bf(v.w); l.w = f2bf(v.w - bf2f(h.w));
  ((ushort4*)hi)[i] = h;
  ((ushort4*)lo)[i] = l;
}

// ---------------- split-bf16 MFMA GEMM: C[M,N] = A[M,K] @ Bw[N,K]^T ----------------
template <int BN>
__global__ __launch_bounds__(256) void gemm_mfma(const unsigned short* __restrict__ Ah,
                                                 const unsigned short* __restrict__ Al,
                                                 const unsigned short* __restrict__ Bh,
                                                 const unsigned short* __restrict__ Bl,
                                                 float* __restrict__ C,
                                                 int M, int N, int K) {
  constexpr int NF = BN / 16;
  const int t = threadIdx.x;
  const int lane = t & 63;
  const int wv = t >> 6;
  const int m0 = blockIdx.y * 128 + wv * 32;  // 4 waves stacked in M
  const int n0 = blockIdx.x * BN;
  const int lr = lane & 15;
  const int kg = lane >> 4;

  const unsigned short* a0h = Ah + (size_t)(m0 + lr) * K + kg * 8;
  const unsigned short* a1h = a0h + (size_t)16 * K;
  const unsigned short* a0l = Al + (size_t)(m0 + lr) * K + kg * 8;
  const unsigned short* a1l = a0l + (size_t)16 * K;
  const unsigned short* bph = Bh + (size_t)(n0 + lr) * K + kg * 8;
  const unsigned short* bpl = Bl + (size_t)(n0 + lr) * K + kg * 8;

  f32x4m acc[2][NF];
#pragma unroll
  for (int i = 0; i < 2; ++i)
#pragma unroll
    for (int f = 0; f < NF; ++f) {
      f32x4m z = {0.f, 0.f, 0.f, 0.f};
      acc[i][f] = z;
    }

  for (int k0 = 0; k0 < K; k0 += 32) {
    bf16x8 ah0 = *(const bf16x8*)(a0h + k0);
    bf16x8 ah1 = *(const bf16x8*)(a1h + k0);
    bf16x8 al0 = *(const bf16x8*)(a0l + k0);
    bf16x8 al1 = *(const bf16x8*)(a1l + k0);
#pragma unroll
    for (int f = 0; f < NF; ++f) {
      bf16x8 vbh = *(const bf16x8*)(bph + (size_t)f * 16 * K + k0);
      bf16x8 vbl = *(const bf16x8*)(bpl + (size_t)f * 16 * K + k0);
      acc[0][f] = __builtin_amdgcn_mfma_f32_16x16x32_bf16(al0, vbh, acc[0][f], 0, 0, 0);
      acc[0][f] = __builtin_amdgcn_mfma_f32_16x16x32_bf16(ah0, vbl, acc[0][f], 0, 0, 0);
      acc[0][f] = __builtin_amdgcn_mfma_f32_16x16x32_bf16(ah0, vbh, acc[0][f], 0, 0, 0);
      acc[1][f] = __builtin_amdgcn_mfma_f32_16x16x32_bf16(al1, vbh, acc[1][f], 0, 0, 0);
      acc[1][f] = __builtin_amdgcn_mfma_f32_16x16x32_bf16(ah1, vbl, acc[1][f], 0, 0, 0);
      acc[1][f] = __builtin_amdgcn_mfma_f32_16x16x32_bf16(ah1, vbh, acc[1][f], 0, 0, 0);
    }
  }
#pragma unroll
  for (int i = 0; i < 2; ++i)
#pragma unroll
    for (int f = 0; f < NF; ++f)
#pragma unroll
      for (int r = 0; r < 4; ++r)
        C[(size_t)(m0 + i * 16 + kg * 4 + r) * N + n0 + f * 16 + lr] = acc[i][f][r];
}

// ---------------- gaussian kernel weights: q_w (× 1/temp), k_w ----------------
__global__ __launch_bounds__(256) void k_gauss(const float* __restrict__ qkv,
                                               const float* __restrict__ centers,
                                               const float* __restrict__ inv_var,
                                               const float* __restrict__ eff_amps,
                                               const float* __restrict__ inv_temp,
                                               float* __restrict__ qw,
                                               float* __restrict__ kw) {
  int gid = blockIdx.x * blockDim.x + threadIdx.x;
  if (gid >= B_ * T_ * H_ * S_) return;
  int s = gid & 15;
  int h = (gid >> 4) & 7;
  int bt = gid >> 7;  // b*T + t
  const float* qrow = qkv + (size_t)bt * 1536 + h * 64;
  const float* krow = qrow + 512;
  const float* c = centers + (h * 16 + s) * 64;
  float qd = 0.f, kd = 0.f;
#pragma unroll
  for (int d = 0; d < 64; d += 4) {
    float4 cv = *(const float4*)(c + d);
    float4 qv = *(const float4*)(qrow + d);
    float4 kv = *(const float4*)(krow + d);
    float t;
    t = qv.x - cv.x; qd += t * t;
    t = qv.y - cv.y; qd += t * t;
    t = qv.z - cv.z; qd += t * t;
    t = qv.w - cv.w; qd += t * t;
    t = kv.x - cv.x; kd += t * t;
    t = kv.y - cv.y; kd += t * t;
    t = kv.z - cv.z; kd += t * t;
    t = kv.w - cv.w; kd += t * t;
  }
  qd = fminf(qd, 100.f);
  kd = fminf(kd, 100.f);
  float iv = inv_var[h * 16 + s];
  float ea = eff_amps[h * 16 + s];
  qw[gid] = __expf(-0.5f * qd * iv) * ea * inv_temp[0];
  kw[gid] = __expf(-0.5f * kd * iv) * ea;
}

__device__ __forceinline__ float dot16(const float4 q[4], const float4 k[4]) {
  return q[0].x * k[0].x + q[0].y * k[0].y + q[0].z * k[0].z + q[0].w * k[0].w +
         q[1].x * k[1].x + q[1].y * k[1].y + q[1].z * k[1].z + q[1].w * k[1].w +
         q[2].x * k[2].x + q[2].y * k[2].y + q[2].z * k[2].z + q[2].w * k[2].w +
         q[3].x * k[3].x + q[3].y * k[3].y + q[3].z * k[3].z + q[3].w * k[3].w;
}

// ---------------- softmax stats: m_i, 1/s_i per (b,h,i) ----------------
__global__ __launch_bounds__(256) void k_stats(const float* __restrict__ qw_g,
                                               const float* __restrict__ kw_g,
                                               float* __restrict__ m_g,
                                               float* __restrict__ is_g) {
  const int x = blockIdx.x;
  const int ic = x & 127;
  const int h = (x >> 7) & 7;
  const int b = x >> 10;
  const int i0 = ic * ITS;
  const int tid = threadIdx.x;

  __shared__ float qw_l[ITS * 16];
  __shared__ float red[4][ITS][2];

  if (tid < 32) {
    int r = tid >> 2, s4 = (tid & 3) * 4;
    *(float4*)&qw_l[r * 16 + s4] =
        *(const float4*)(qw_g + (((size_t)(b * T_ + i0 + r) * H_ + h) * S_ + s4));
  }
  __syncthreads();

  float m[ITS], s[ITS];
#pragma unroll
  for (int r = 0; r < ITS; ++r) { m[r] = -1e30f; s[r] = 0.f; }

  for (int c = 0; c < T_ / 256; ++c) {
    int j = c * 256 + tid;
    const float* kp = kw_g + ((size_t)(b * T_ + j) * H_ + h) * S_;
    float4 k4[4];
    k4[0] = *(const float4*)(kp);
    k4[1] = *(const float4*)(kp + 4);
    k4[2] = *(const float4*)(kp + 8);
    k4[3] = *(const float4*)(kp + 12);
#pragma unroll
    for (int r = 0; r < ITS; ++r) {
      float4 q4[4];
      q4[0] = *(const float4*)&qw_l[r * 16 + 0];
      q4[1] = *(const float4*)&qw_l[r * 16 + 4];
      q4[2] = *(const float4*)&qw_l[r * 16 + 8];
      q4[3] = *(const float4*)&qw_l[r * 16 + 12];
      float l = dot16(q4, k4);
      float mn = fmaxf(m[r], l);
      s[r] = s[r] * __expf(m[r] - mn) + __expf(l - mn);
      m[r] = mn;
    }
  }
#pragma unroll
  for (int o = 1; o < 64; o <<= 1) {
#pragma unroll
    for (int r = 0; r < ITS; ++r) {
      float m2 = __shfl_xor(m[r], o);
      float s2 = __shfl_xor(s[r], o);
      float mn = fmaxf(m[r], m2);
      s[r] = s[r] * __expf(m[r] - mn) + s2 * __expf(m2 - mn);
      m[r] = mn;
    }
  }
  int wv = tid >> 6;
  if ((tid & 63) == 0) {
#pragma unroll
    for (int r = 0; r < ITS; ++r) { red[wv][r][0] = m[r]; red[wv][r][1] = s[r]; }
  }
  __syncthreads();
  if (tid < ITS) {
    float mf = red[0][tid][0], sf = red[0][tid][1];
#pragma unroll
    for (int w = 1; w < 4; ++w) {
      float m2 = red[w][tid][0], s2 = red[w][tid][1];
      float mn = fmaxf(mf, m2);
      sf = sf * __expf(mf - mn) + s2 * __expf(m2 - mn);
      mf = mn;
    }
    size_t o = (size_t)(b * H_ + h) * T_ + i0 + tid;
    m_g[o] = mf;
    is_g[o] = 1.f / sf;
  }
}

// ---------------- attn writer: recompute logits, write attn only ----------------
__global__ __launch_bounds__(256, 4) void k_attnw(const float* __restrict__ qw_g,
                                                  const float* __restrict__ kw_g,
                                                  const float* __restrict__ m_g,
                                                  const float* __restrict__ is_g,
                                                  float* __restrict__ attn) {
  const int x = blockIdx.x;
  const int jt = x & 3;
  const int it = (x >> 2) & 127;
  const int b = x >> 9;
  const int i0 = it * ITW;
  const int jbase = jt * 256;
  const int tid = threadIdx.x;

  __shared__ float qw_l[ITW][H_ * S_];     // 4 KB
  __shared__ float msl[ITW][H_];
  __shared__ float isl[ITW][H_];
  __shared__ float tile[ITW][H_][68];      // 17.4 KB

  {
    int f = tid * 4;
    int r = f >> 7, c = f & 127;
    *(float4*)&qw_l[r][c] = *(const float4*)(qw_g + ((size_t)(b * T_ + i0 + r) * 128 + c));
  }
  if (tid < 64) {
    int r = tid >> 3, hh = tid & 7;
    size_t o = (size_t)(b * H_ + hh) * T_ + i0 + r;
    msl[r][hh] = m_g[o];
    isl[r][hh] = is_g[o];
  }
  __syncthreads();

  const int h = tid >> 5;
  const int jq = tid & 31;
  const float* kw_b = kw_g + (size_t)b * T_ * (H_ * S_);
  float* attn_b = attn + (size_t)(b * T_ + i0) * (T_ * H_);

  for (int st = 0; st < 4; ++st) {
    const int j0 = jbase + st * 64;
    const float* kp = kw_b + ((size_t)(j0 + jq * 2) * H_ + h) * S_;
    float4 ka[4], kb[4];
    ka[0] = *(const float4*)(kp);       ka[1] = *(const float4*)(kp + 4);
    ka[2] = *(const float4*)(kp + 8);   ka[3] = *(const float4*)(kp + 12);
    kb[0] = *(const float4*)(kp + 128); kb[1] = *(const float4*)(kp + 132);
    kb[2] = *(const float4*)(kp + 136); kb[3] = *(const float4*)(kp + 140);
#pragma unroll
    for (int r = 0; r < ITW; ++r) {
      float4 q4[4];
      q4[0] = *(const float4*)&qw_l[r][h * 16 + 0];
      q4[1] = *(const float4*)&qw_l[r][h * 16 + 4];
      q4[2] = *(const float4*)&qw_l[r][h * 16 + 8];
      q4[3] = *(const float4*)&qw_l[r][h * 16 + 12];
      float la = dot16(q4, ka);
      float lb = dot16(q4, kb);
      float mm = msl[r][h], ii = isl[r][h];
      *(float2*)&tile[r][h][jq * 2] =
          make_float2(__expf(la - mm) * ii, __expf(lb - mm) * ii);
    }
    __syncthreads();
#pragma unroll
    for (int l = 0; l < 4; ++l) {
      int f = (l * 256 + tid) * 4;
      int r = f >> 9;
      int rem = f & 511;
      int jl = rem >> 3;
      int h0 = rem & 7;  // 0 or 4
      float4 v;
      v.x = tile[r][h0 + 0][jl];
      v.y = tile[r][h0 + 1][jl];
      v.z = tile[r][h0 + 2][jl];
      v.w = tile[r][h0 + 3][jl];
      *(float4*)(attn_b + (size_t)r * (T_ * H_) + (size_t)(j0 + jl) * H_ + h0) = v;
    }
    __syncthreads();
  }
}

// ---------------- PV via MFMA with P-in-registers (v4) ----------------
// Waves = (I = i-frag 0..1, S = k-step 0..1). Each lane computes its own MFMA
// A-fragment of P in REGISTERS (8 consecutive j for row i = lane&15 — exactly
// the verified A layout), from VALU logits fed by XOR-swizzled fp32 kw LDS.
// Phase 2: mfma_f32_16x16x32_bf16, split-bf16 P and V (3 products, err ~2^-17).
// V stays fp32 in d-quad-XOR-swizzled LDS; B-frag built by scalar reads + cvt_pk.
// qw/m/is pinned via asm (round-10's VGPR=64 showed the compiler remat'ing the
// qw loads into the loop -> FETCH 30MB). One S-merge after the chunk loop.
__global__ __launch_bounds__(256, 4) void k_pv(const float* __restrict__ qkv,
                                               const float* __restrict__ qw_g,
                                               const float* __restrict__ kw_g,
                                               const float* __restrict__ m_g,
                                               const float* __restrict__ is_g,
                                               unsigned short* __restrict__ oph,
                                               unsigned short* __restrict__ opl) {
  const int bid = blockIdx.x;
  const int xcd = bid & 7;
  const int qq = bid >> 3;             // 0..127
  const int p = xcd * 4 + (qq & 3);    // panel 0..31
  const int ib = qq >> 2;              // 0..31
  const int b = p >> 3;
  const int h = p & 7;
  const int i0 = ib * PVI;
  const int t = threadIdx.x;
  const int lane = t & 63;
  const int w = t >> 6;
  const int I = w >> 1;                // i-frag
  const int S = w & 1;                 // k-step (32-j half of chunk)
  const int lr = lane & 15;
  const int kg = lane >> 4;

  __shared__ float kw_sw[PVJ][16];     // 4 KB; s4-block ^= (j>>3)&3
  __shared__ float Vl[PVJ][64];        // 16 KB; d-quad ^= ((j>>3)&3)<<2; merge scratch

  // ---- per-lane invariants: qw row, m, 1/s (asm-pinned against remat) ----
  const int irow = I * 16 + lr;
  float qwr[16];
  {
    const float* qp = qw_g + (((size_t)(b * T_ + i0 + irow) * H_ + h) * S_);
#pragma unroll
    for (int s4 = 0; s4 < 4; ++s4) {
      float4 v = *(const float4*)(qp + s4 * 4);
      qwr[s4 * 4 + 0] = v.x; qwr[s4 * 4 + 1] = v.y;
      qwr[s4 * 4 + 2] = v.z; qwr[s4 * 4 + 3] = v.w;
    }
  }
  float mr = m_g[(size_t)(b * H_ + h) * T_ + i0 + irow];
  float isr = is_g[(size_t)(b * H_ + h) * T_ + i0 + irow];
#pragma unroll
  for (int s = 0; s < 16; ++s) asm volatile("" : "+v"(qwr[s]));
  asm volatile("" : "+v"(mr));
  asm volatile("" : "+v"(isr));

  f32x4m acc[4];
#pragma unroll
  for (int f = 0; f < 4; ++f) { f32x4m z = {0.f, 0.f, 0.f, 0.f}; acc[f] = z; }

  for (int jc = 0; jc < T_ / PVJ; ++jc) {
    const int j0 = jc * PVJ;
    __syncthreads();  // prior chunk's readers done
    // stage kw (swizzled): thread j = t>>2, s4-group = t&3
    {
      int j = t >> 2, s4g = t & 3;
      float4 v = *(const float4*)(kw_g + (((size_t)(b * T_ + j0 + j) * H_ + h) * S_ + s4g * 4));
      int blk = s4g ^ ((j >> 3) & 3);
      *(float4*)&kw_sw[j][blk * 4] = v;
    }
    // stage V (swizzled): 64 j x 64 d
    {
      int j = t >> 4, dq = t & 15;
#pragma unroll
      for (int u = 0; u < 4; ++u) {
        int jj = j + u * 16;
        float4 v = *(const float4*)(qkv + (size_t)(b * T_ + j0 + jj) * 1536 +
                                    1024 + h * 64 + dq * 4);
        int dqs = dq ^ (((jj >> 3) & 3) << 2);
        *(float4*)&Vl[jj][dqs * 4] = v;
      }
    }
    __syncthreads();
    // ---- phase 1: logits -> P A-frag (hi/lo bf16) in registers ----
    union UA { unsigned u[4]; bf16x8 v; } AH, AL;
#pragma unroll
    for (int u2 = 0; u2 < 4; ++u2) {
      float pv2[2];
#pragma unroll
      for (int e = 0; e < 2; ++e) {
        int jr = S * 32 + kg * 8 + u2 * 2 + e;   // j within chunk
        int g = (jr >> 3) & 3;
        float d = 0.f;
#pragma unroll
        for (int s4 = 0; s4 < 4; ++s4) {
          float4 kv = *(const float4*)&kw_sw[jr][(s4 ^ g) * 4];
          d += qwr[s4 * 4 + 0] * kv.x + qwr[s4 * 4 + 1] * kv.y +
               qwr[s4 * 4 + 2] * kv.z + qwr[s4 * 4 + 3] * kv.w;
        }
        pv2[e] = __expf(d - mr) * isr;
      }
      split2(pv2[0], pv2[1], AH.u[u2], AL.u[u2]);
    }
    // ---- phase 2: 4 d-frags x 3 split products on the matrix pipe ----
#pragma unroll
    for (int f = 0; f < 4; ++f) {
      int dcol = f * 16 + lr;
      int dq = dcol >> 2, dw = dcol & 3;
      float vv[8];
#pragma unroll
      for (int u = 0; u < 8; ++u) {
        int jr = S * 32 + kg * 8 + u;
        int dqs = dq ^ (((jr >> 3) & 3) << 2);
        vv[u] = Vl[jr][dqs * 4 + dw];
      }
      union UB { unsigned u[4]; bf16x8 v; } BH, BL;
#pragma unroll
      for (int u2 = 0; u2 < 4; ++u2)
        split2(vv[u2 * 2], vv[u2 * 2 + 1], BH.u[u2], BL.u[u2]);
      acc[f] = __builtin_amdgcn_mfma_f32_16x16x32_bf16(AL.v, BH.v, acc[f], 0, 0, 0);
      acc[f] = __builtin_amdgcn_mfma_f32_16x16x32_bf16(AH.v, BL.v, acc[f], 0, 0, 0);
      acc[f] = __builtin_amdgcn_mfma_f32_16x16x32_bf16(AH.v, BH.v, acc[f], 0, 0, 0);
    }
  }
  // ---- merge S=0 + S=1 partials, convert, store bf16 hi/lo ----
  __syncthreads();
  float* mg = &Vl[0][0];  // reuse as scratch (stride 17 words: conflict-light)
  if (S == 1) {
    float* dst = mg + (size_t)(I * 64 + lane) * 17;
#pragma unroll
    for (int f = 0; f < 4; ++f)
#pragma unroll
      for (int r = 0; r < 4; ++r) dst[f * 4 + r] = acc[f][r];
  }
  __syncthreads();
  if (S == 0) {
    const float* src = mg + (size_t)(I * 64 + lane) * 17;
#pragma unroll
    for (int f = 0; f < 4; ++f) {
#pragma unroll
      for (int r = 0; r < 4; ++r) {
        float o = acc[f][r] + src[f * 4 + r];
        unsigned short hh = f2bf(o);
        unsigned short ll = f2bf(o - bf2f(hh));
        size_t idx = (size_t)(b * T_ + i0 + I * 16 + kg * 4 + r) * D_ + h * HD_ + f * 16 + lr;
        oph[idx] = hh;
        opl[idx] = ll;
      }
    }
  }
}

extern "C" void kernel_launch(void* const* d_in, const int* in_sizes, int n_in,
                              void* d_out, int out_size, void* d_ws, size_t ws_size,
                              hipStream_t stream) {
  const float* x = (const float*)d_in[0];
  const float* qkv_w = (const float*)d_in[1];
  const float* out_w = (const float*)d_in[2];
  const float* base_c = (const float*)d_in[3];
  const float* deltas = (const float*)d_in[4];
  const float* log_sc = (const float*)d_in[5];
  const float* log_am = (const float*)d_in[6];
  const float* move_p = (const float*)d_in[7];
  const float* temp = (const float*)d_in[8];

  float* out = (float*)d_out;                    // B*T*D
  float* attn = out + (size_t)B_ * T_ * D_;      // B*T*T*H

  float* ws = (float*)d_ws;
  float* qkv = ws;                                          // 6,291,456 f
  float* qw = qkv + 6291456;                                // 524,288
  float* kw = qw + 524288;                                  // 524,288
  float* centers = kw + 524288;                             // 8,192
  float* inv_var = centers + 8192;                          // 128
  float* eff_amps = inv_var + 128;                          // 128
  float* inv_temp = eff_amps + 128;                         // 4
  float* m_g = inv_temp + 4;                                // 32,768
  float* is_g = m_g + 32768;                                // 32,768
  unsigned short* xh = (unsigned short*)(is_g + 32768);     // 2,097,152 us
  unsigned short* xl = xh + 2097152;                        // 2,097,152
  unsigned short* wh = xl + 2097152;                        // 786,432
  unsigned short* wl = wh + 786432;                         // 786,432
  unsigned short* owh = wl + 786432;                        // 262,144
  unsigned short* owl = owh + 262144;                       // 262,144
  unsigned short* oph = owl + 262144;                       // 2,097,152
  unsigned short* opl = oph + 2097152;                      // 2,097,152

  k_params<<<32, 256, 0, stream>>>(base_c, deltas, log_sc, log_am, move_p, temp,
                                   centers, inv_var, eff_amps, inv_temp);
  k_split<<<2048, 256, 0, stream>>>(x, xh, xl, 2097152 / 4);
  k_split<<<768, 256, 0, stream>>>(qkv_w, wh, wl, 786432 / 4);
  k_split<<<256, 256, 0, stream>>>(out_w, owh, owl, 262144 / 4);

  dim3 g1(1536 / 64, 4096 / 128);   // 24 x 32 = 768 WGs
  gemm_mfma<64><<<g1, 256, 0, stream>>>(xh, xl, wh, wl, qkv, B_ * T_, 3 * D_, D_);

  k_gauss<<<(B_ * T_ * H_ * S_) / 256, 256, 0, stream>>>(qkv, centers, inv_var,
                                                         eff_amps, inv_temp, qw, kw);
  k_stats<<<B_ * H_ * (T_ / ITS), 256, 0, stream>>>(qw, kw, m_g, is_g);
  k_attnw<<<B_ * (T_ / ITW) * 4, 256, 0, stream>>>(qw, kw, m_g, is_g, attn);
  k_pv<<<B_ * H_ * (T_ / PVI), 256, 0, stream>>>(qkv, qw, kw, m_g, is_g, oph, opl);

  dim3 g2(512 / 64, 4096 / 128);    // 8 x 32 = 256 WGs
  gemm_mfma<64><<<g2, 256, 0, stream>>>(oph, opl, owh, owl, out, B_ * T_, D_, D_);
}